// Round 1
// baseline (1539.262 us; speedup 1.0000x reference)
//
#include <hip/hip_runtime.h>
#include <hip/hip_bf16.h>

#define L2E 1.44269504088896f

// ---------------- pack adj -> bitmask ----------------
__global__ __launch_bounds__(256) void pack_k(const int* __restrict__ adj,
                                              unsigned long long* __restrict__ mask) {
    size_t idx = (size_t)blockIdx.x * 256 + threadIdx.x;
    int v = adj[idx];
    unsigned long long b = __ballot(v > 0);
    if ((threadIdx.x & 63) == 0) mask[idx >> 6] = b;
}

// ---------------- generic tiled f32 GEMM: C = A[MxK] @ B[KxN] (+bias) ----------------
__global__ __launch_bounds__(256) void gemm_k(const float* __restrict__ A,
                                              const float* __restrict__ B,
                                              const float* __restrict__ bias,
                                              float* __restrict__ C,
                                              int M, int N, int K,
                                              long long sB, long long sC) {
    constexpr int BM = 64, BN = 64, BK = 32;
    const float* Bz = B + (long long)blockIdx.z * sB;
    float* Cz = C + (long long)blockIdx.z * sC;
    __shared__ float As[BK][BM + 4];
    __shared__ float Bs[BK][BN + 4];
    int tid = threadIdx.x;
    int tx = tid & 15, ty = tid >> 4;
    int row0 = blockIdx.x * BM, col0 = blockIdx.y * BN;
    float acc[4][4] = {};
    for (int k0 = 0; k0 < K; k0 += BK) {
        for (int t = tid; t < BM * BK; t += 256) {
            int mm = t >> 5, kk = t & 31;
            As[kk][mm] = A[(size_t)(row0 + mm) * K + k0 + kk];
        }
        for (int t = tid; t < BK * BN; t += 256) {
            int kk = t >> 6, nn = t & 63;
            int c = col0 + nn;
            Bs[kk][nn] = (c < N) ? Bz[(size_t)(k0 + kk) * N + c] : 0.f;
        }
        __syncthreads();
#pragma unroll
        for (int kk = 0; kk < BK; kk++) {
            float4 a4 = *(const float4*)&As[kk][ty * 4];
            float4 b4 = *(const float4*)&Bs[kk][tx * 4];
            float av[4] = {a4.x, a4.y, a4.z, a4.w};
            float bv[4] = {b4.x, b4.y, b4.z, b4.w};
#pragma unroll
            for (int u = 0; u < 4; u++)
#pragma unroll
                for (int v = 0; v < 4; v++) acc[u][v] = fmaf(av[u], bv[v], acc[u][v]);
        }
        __syncthreads();
    }
#pragma unroll
    for (int u = 0; u < 4; u++)
#pragma unroll
        for (int v = 0; v < 4; v++) {
            int c = col0 + tx * 4 + v;
            if (c < N) {
                float o = acc[u][v] + (bias ? bias[c] : 0.f);
                Cz[(size_t)(row0 + ty * 4 + u) * N + c] = o;
            }
        }
}

// ---------------- f1/f2 = Wh @ a[:D], Wh @ a[D:] ----------------
__global__ __launch_bounds__(256) void fvec_k(const float* __restrict__ Wh,
                                              const float* __restrict__ a,
                                              float* __restrict__ f1, float* __restrict__ f2,
                                              int M, int D, long long sWh, long long sa) {
    int zz = blockIdx.y;
    const float* W = Wh + (long long)zz * sWh;
    const float* az = a + (long long)zz * sa;
    int i = blockIdx.x * 256 + threadIdx.x;
    if (i >= M) return;
    float s1 = 0.f, s2 = 0.f;
    for (int k = 0; k < D; k++) {
        float ww = W[(size_t)i * D + k];
        s1 = fmaf(ww, az[k], s1);
        s2 = fmaf(ww, az[D + k], s2);
    }
    f1[(size_t)zz * M + i] = s1;
    f2[(size_t)zz * M + i] = s2;
}

// ---------------- per-batch max of f2 ----------------
__global__ __launch_bounds__(256) void rmax_k(const float* __restrict__ f2,
                                              float* __restrict__ out, int M, long long s) {
    int zz = blockIdx.x;
    const float* p = f2 + (long long)zz * s;
    float m = -1e30f;
    for (int t = threadIdx.x; t < M; t += 256) m = fmaxf(m, p[t]);
    __shared__ float red[256];
    red[threadIdx.x] = m;
    __syncthreads();
    for (int off = 128; off > 0; off >>= 1) {
        if (threadIdx.x < off) red[threadIdx.x] = fmaxf(red[threadIdx.x], red[threadIdx.x + off]);
        __syncthreads();
    }
    if (threadIdx.x == 0) out[zz] = red[0];
}

// ---------------- fused masked-softmax attention aggregation ----------------
// MODE 0: per-head full-j pass, out = elu(attn@Wh) written into hc[i][y*64+f]
// MODE 1: j-chunk partial pass, out = partial unnormalized sums + partial Z
template <int FOUT, int MODE>
__global__ void __launch_bounds__(128) attn_k(const float* __restrict__ WhB,
                                              const float* __restrict__ f1B,
                                              const float* __restrict__ f2B,
                                              const float* __restrict__ M2B,
                                              const unsigned long long* __restrict__ mask,
                                              float* __restrict__ outB,
                                              float* __restrict__ ZB,
                                              int N, int jchunk_len) {
    constexpr int ROWS = 64, FG = 2, TJ = 128;
    constexpr int FT = FOUT / FG;
    const int tid = threadIdx.x;
    const int il = tid & 63;
    const int fg = tid >> 6;
    const int y = blockIdx.y;
    const int i = blockIdx.x * ROWS + il;

    const float* Wh = WhB;
    const float* f1p = f1B;
    const float* f2p = f2B;
    const float* M2p = M2B;
    int jlo = 0, jhi = N;
    if constexpr (MODE == 0) {
        Wh += (size_t)y * N * FOUT;
        f1p += (size_t)y * N;
        f2p += (size_t)y * N;
        M2p += y;
    } else {
        jlo = y * jchunk_len;
        jhi = jlo + jchunk_len;
    }

    float f1i = f1p[i];
    float M2 = M2p[0];
    float t0 = f1i + M2;
    float m = fmaxf(t0, 0.2f * t0);                 // lrelu upper-bound row max
    float Pp = exp2f(L2E * (f1i - m));              // e^{f1-m}
    float Nn = exp2f(L2E * (0.2f * f1i - m));       // e^{0.2 f1 - m}
    float T = exp2f(-L2E * f1i);                    // e^{-f1}; p_j > T  <=>  f1+f2 > 0

    __shared__ float Whs[TJ][FOUT];
    __shared__ float2 pns[TJ];

    float acc[FT];
#pragma unroll
    for (int k = 0; k < FT; k++) acc[k] = 0.f;
    float Z = 0.f;

    const unsigned long long* mrow = mask + (size_t)i * (N >> 6);

    for (int jt = jlo; jt < jhi; jt += TJ) {
        const float4* src = (const float4*)(Wh + (size_t)jt * FOUT);
        float4* dst = (float4*)(&Whs[0][0]);
        for (int t = tid; t < TJ * FOUT / 4; t += 128) dst[t] = src[t];
        for (int t = tid; t < TJ; t += 128) {
            float f2 = f2p[jt + t];
            pns[t] = make_float2(exp2f(L2E * f2), exp2f(L2E * 0.2f * f2));
        }
        __syncthreads();
#pragma unroll
        for (int h2 = 0; h2 < 2; ++h2) {
            unsigned long long mw = mrow[(jt >> 6) + h2];
#pragma unroll 4
            for (int jj2 = 0; jj2 < 64; ++jj2) {
                int jj = h2 * 64 + jj2;
                float2 pn = pns[jj];
                float w = (pn.x > T) ? Pp * pn.x : Nn * pn.y;
                w = (mw & 1ull) ? w : 0.0f;
                mw >>= 1;
                Z += w;
                const float* wr = &Whs[jj][fg * FT];
#pragma unroll
                for (int k = 0; k < FT; k++) acc[k] = fmaf(w, wr[k], acc[k]);
            }
        }
        __syncthreads();
    }

    if constexpr (MODE == 0) {
        float inv = 1.0f / Z;
        float* orow = outB + (size_t)i * (8 * FOUT) + (size_t)y * FOUT + fg * FT;
#pragma unroll
        for (int k = 0; k < FT; k++) {
            float o = acc[k] * inv;
            o = (o > 0.f) ? o : (__expf(o) - 1.f);  // elu
            orow[k] = o;
        }
    } else {
        float* orow = outB + ((size_t)y * N + i) * FOUT + fg * FT;
#pragma unroll
        for (int k = 0; k < FT; k++) orow[k] = acc[k];
        if (fg == 0) ZB[(size_t)y * N + i] = Z;
    }
}

// ---------------- combine j-split partials ----------------
__global__ __launch_bounds__(256) void comb2_k(const float* __restrict__ part,
                                               const float* __restrict__ Zp,
                                               const float* __restrict__ orig,
                                               float* __restrict__ zout, int N) {
    int id = blockIdx.x * 256 + threadIdx.x;  // N*64
    int i = id >> 6, f = id & 63;
    float Zs = 0.f, s = 0.f;
#pragma unroll
    for (int c = 0; c < 8; c++) Zs += Zp[(size_t)c * N + i];
#pragma unroll
    for (int c = 0; c < 8; c++) s += part[((size_t)c * N + i) * 64 + f];
    zout[id] = s / Zs + orig[id];
}

__global__ __launch_bounds__(256) void comb1_k(const float* __restrict__ part,
                                               const float* __restrict__ Zp,
                                               float* __restrict__ cls, int N) {
    int id = blockIdx.x * 256 + threadIdx.x;  // N*16
    int i = id >> 4, f = id & 15;
    float Zs = 0.f, s = 0.f;
#pragma unroll
    for (int c = 0; c < 8; c++) Zs += Zp[(size_t)c * N + i];
#pragma unroll
    for (int c = 0; c < 8; c++) s += part[((size_t)c * N + i) * 16 + f];
    float o = s / Zs;
    cls[id] = (o > 0.f) ? o : (expf(o) - 1.f);  // elu
}

// ---------------- log_softmax over 16 classes ----------------
__global__ __launch_bounds__(256) void lsm_k(const float* __restrict__ cls,
                                             float* __restrict__ out, int N) {
    int i = blockIdx.x * 256 + threadIdx.x;
    if (i >= N) return;
    float v[16];
    float m = -1e30f;
#pragma unroll
    for (int k = 0; k < 16; k++) {
        v[k] = cls[(size_t)i * 16 + k];
        m = fmaxf(m, v[k]);
    }
    float s = 0.f;
#pragma unroll
    for (int k = 0; k < 16; k++) s += expf(v[k] - m);
    float l = m + logf(s);
#pragma unroll
    for (int k = 0; k < 16; k++) out[(size_t)i * 16 + k] = v[k] - l;
}

// ---------------- result2 = z @ w_deg + b_deg ----------------
__global__ __launch_bounds__(256) void r2_k(const float* __restrict__ z,
                                            const float* __restrict__ wd,
                                            const float* __restrict__ bd,
                                            float* __restrict__ out, int N) {
    int i = blockIdx.x * 256 + threadIdx.x;
    if (i >= N) return;
    float s = bd[0];
#pragma unroll
    for (int k = 0; k < 64; k++) s = fmaf(z[(size_t)i * 64 + k], wd[k], s);
    out[i] = s;
}

extern "C" void kernel_launch(void* const* d_in, const int* in_sizes, int n_in,
                              void* d_out, int out_size, void* d_ws, size_t ws_size,
                              hipStream_t stream) {
    const float* x = (const float*)d_in[0];
    const int* adj = (const int*)d_in[1];
    const float* W_att = (const float*)d_in[2];
    const float* a_att = (const float*)d_in[3];
    const float* W_out1 = (const float*)d_in[4];
    const float* a_out1 = (const float*)d_in[5];
    const float* W_out2 = (const float*)d_in[6];
    const float* a_out2 = (const float*)d_in[7];
    const float* W_down = (const float*)d_in[8];
    const float* b_down = (const float*)d_in[9];
    const float* w_deg = (const float*)d_in[10];
    const float* b_deg = (const float*)d_in[11];
    const float* W_deg3 = (const float*)d_in[12];
    const float* b_deg3 = (const float*)d_in[13];
    float* out = (float*)d_out;

    constexpr int N = 4096, NF = 512, NH = 64, NC = 16, H = 8, DM = 128;

    char* wp = (char*)d_ws;
    auto alloc = [&](size_t b) {
        char* p = wp;
        wp += (b + 255) & ~(size_t)255;
        return p;
    };
    unsigned long long* mask = (unsigned long long*)alloc((size_t)N * N / 8);
    float* Wh = (float*)alloc((size_t)H * N * NH * 4);
    float* f1h = (float*)alloc((size_t)H * N * 4);
    float* f2h = (float*)alloc((size_t)H * N * 4);
    float* M2 = (float*)alloc(256);
    float* hc = (float*)alloc((size_t)N * NF * 4);
    float* orig = (float*)alloc((size_t)N * NH * 4);
    float* Wh1 = (float*)alloc((size_t)N * NC * 4);
    float* Wh2 = (float*)alloc((size_t)N * NH * 4);
    float* f1o1 = (float*)alloc((size_t)N * 4);
    float* f2o1 = (float*)alloc((size_t)N * 4);
    float* f1o2 = (float*)alloc((size_t)N * 4);
    float* f2o2 = (float*)alloc((size_t)N * 4);
    float* part1 = (float*)alloc((size_t)8 * N * NC * 4);
    float* Z1 = (float*)alloc((size_t)8 * N * 4);
    float* part2 = (float*)alloc((size_t)8 * N * NH * 4);
    float* Z2 = (float*)alloc((size_t)8 * N * 4);
    float* zbuf = (float*)alloc((size_t)N * NH * 4);
    float* cls = (float*)alloc((size_t)N * NC * 4);

    // 1. pack adjacency into bitmask (2 MB, L2-resident for all later passes)
    pack_k<<<(size_t)N * N / 256, 256, 0, stream>>>(adj, mask);
    // 2. Wh[h] = x @ W_att[h]  (batched over heads);  orig = x @ W_down + b_down
    gemm_k<<<dim3(N / 64, 1, H), 256, 0, stream>>>(x, W_att, nullptr, Wh, N, NH, NF,
                                                   (long long)NF * NH, (long long)N * NH);
    gemm_k<<<dim3(N / 64, 1, 1), 256, 0, stream>>>(x, W_down, b_down, orig, N, NH, NF, 0, 0);
    // 3. f1/f2 per head + global max of f2 per head
    fvec_k<<<dim3(N / 256, H), 256, 0, stream>>>(Wh, a_att, f1h, f2h, N, NH,
                                                 (long long)N * NH, 2 * NH);
    rmax_k<<<H, 256, 0, stream>>>(f2h, M2, N, N);
    // 4. 8-head fused masked-softmax attention -> hc (with elu), [4096,512]
    attn_k<64, 0><<<dim3(N / 64, H), 128, 0, stream>>>(Wh, f1h, f2h, M2, mask, hc, nullptr, N, 0);
    // 5. second-layer projections
    gemm_k<<<dim3(N / 64, 1, 1), 256, 0, stream>>>(hc, W_out2, nullptr, Wh2, N, NH, NF, 0, 0);
    gemm_k<<<dim3(N / 64, 1, 1), 256, 0, stream>>>(hc, W_out1, nullptr, Wh1, N, NC, NF, 0, 0);
    fvec_k<<<dim3(N / 256, 1), 256, 0, stream>>>(Wh1, a_out1, f1o1, f2o1, N, NC, 0, 0);
    fvec_k<<<dim3(N / 256, 1), 256, 0, stream>>>(Wh2, a_out2, f1o2, f2o2, N, NH, 0, 0);
    rmax_k<<<1, 256, 0, stream>>>(f2o1, M2 + 8, N, 0);
    rmax_k<<<1, 256, 0, stream>>>(f2o2, M2 + 9, N, 0);
    // 6. out1/out2 attention, j-split 8-way for occupancy (shared m_i -> trivial combine)
    attn_k<64, 1><<<dim3(N / 64, 8), 128, 0, stream>>>(Wh2, f1o2, f2o2, M2 + 9, mask, part2, Z2,
                                                       N, N / 8);
    attn_k<16, 1><<<dim3(N / 64, 8), 128, 0, stream>>>(Wh1, f1o1, f2o1, M2 + 8, mask, part1, Z1,
                                                       N, N / 8);
    comb2_k<<<(size_t)N * 64 / 256, 256, 0, stream>>>(part2, Z2, orig, zbuf, N);
    comb1_k<<<(size_t)N * 16 / 256, 256, 0, stream>>>(part1, Z1, cls, N);
    // 7. outputs
    lsm_k<<<N / 256, 256, 0, stream>>>(cls, out, N);
    r2_k<<<N / 256, 256, 0, stream>>>(zbuf, w_deg, b_deg, out + (size_t)N * NC, N);
    gemm_k<<<dim3(N / 64, 2, 1), 256, 0, stream>>>(zbuf, W_deg3, b_deg3,
                                                   out + (size_t)N * NC + N, N, DM, NH, 0, 0);
}

// Round 3
// 684.067 us; speedup vs baseline: 2.2502x; 2.2502x over previous
//
#include <hip/hip_runtime.h>
#include <hip/hip_bf16.h>

#define L2E 1.44269504088896f

typedef __attribute__((ext_vector_type(8))) short short8v;
typedef __attribute__((ext_vector_type(4))) float float4v;

__device__ __forceinline__ void gld16(void* lds, const void* gp) {
    __builtin_amdgcn_global_load_lds(
        (const __attribute__((address_space(1))) unsigned int*)gp,
        (__attribute__((address_space(3))) unsigned int*)lds, 16, 0, 0);
}

__device__ __forceinline__ unsigned int pkbf(float a, float b) {
    unsigned int r;
    asm("v_cvt_pk_bf16_f32 %0, %1, %2" : "=v"(r) : "v"(a), "v"(b));
    return r;
}

// ---------------- pack adj -> bitmask ----------------
__global__ __launch_bounds__(256) void pack_k(const int* __restrict__ adj,
                                              unsigned long long* __restrict__ mask) {
    size_t idx = (size_t)blockIdx.x * 256 + threadIdx.x;
    int v = adj[idx];
    unsigned long long b = __ballot(v > 0);
    if ((threadIdx.x & 63) == 0) mask[idx >> 6] = b;
}

// ---------------- generic tiled f32 GEMM: C = A[MxK] @ B[KxN] (+bias) ----------------
__global__ __launch_bounds__(256) void gemm_k(const float* __restrict__ A,
                                              const float* __restrict__ B,
                                              const float* __restrict__ bias,
                                              float* __restrict__ C,
                                              int M, int N, int K,
                                              long long sB, long long sC) {
    constexpr int BM = 64, BN = 64, BK = 32;
    const float* Bz = B + (long long)blockIdx.z * sB;
    float* Cz = C + (long long)blockIdx.z * sC;
    __shared__ float As[BK][BM + 4];
    __shared__ float Bs[BK][BN + 4];
    int tid = threadIdx.x;
    int tx = tid & 15, ty = tid >> 4;
    int row0 = blockIdx.x * BM, col0 = blockIdx.y * BN;
    float acc[4][4] = {};
    for (int k0 = 0; k0 < K; k0 += BK) {
        for (int t = tid; t < BM * BK; t += 256) {
            int mm = t >> 5, kk = t & 31;
            As[kk][mm] = A[(size_t)(row0 + mm) * K + k0 + kk];
        }
        for (int t = tid; t < BK * BN; t += 256) {
            int kk = t >> 6, nn = t & 63;
            int c = col0 + nn;
            Bs[kk][nn] = (c < N) ? Bz[(size_t)(k0 + kk) * N + c] : 0.f;
        }
        __syncthreads();
#pragma unroll
        for (int kk = 0; kk < BK; kk++) {
            float4 a4 = *(const float4*)&As[kk][ty * 4];
            float4 b4 = *(const float4*)&Bs[kk][tx * 4];
            float av[4] = {a4.x, a4.y, a4.z, a4.w};
            float bv[4] = {b4.x, b4.y, b4.z, b4.w};
#pragma unroll
            for (int u = 0; u < 4; u++)
#pragma unroll
                for (int v = 0; v < 4; v++) acc[u][v] = fmaf(av[u], bv[v], acc[u][v]);
        }
        __syncthreads();
    }
#pragma unroll
    for (int u = 0; u < 4; u++)
#pragma unroll
        for (int v = 0; v < 4; v++) {
            int c = col0 + tx * 4 + v;
            if (c < N) {
                float o = acc[u][v] + (bias ? bias[c] : 0.f);
                Cz[(size_t)(row0 + ty * 4 + u) * N + c] = o;
            }
        }
}

// ---------------- batched transpose + bf16 convert: src [M][F] f32 -> dst [F][M] bf16 ----
__global__ __launch_bounds__(256) void tpose_k(const float* __restrict__ src,
                                               unsigned short* __restrict__ dst,
                                               int M, int F) {
    src += (size_t)blockIdx.z * M * F;
    dst += (size_t)blockIdx.z * F * M;
    __shared__ float t[64][17];
    int j0 = blockIdx.x * 64, f0 = blockIdx.y * 16;
    int tid = threadIdx.x;
    int rr = tid >> 2, c0 = (tid & 3) * 4;
    float4 v = *(const float4*)&src[(size_t)(j0 + rr) * F + f0 + c0];
    t[rr][c0 + 0] = v.x;
    t[rr][c0 + 1] = v.y;
    t[rr][c0 + 2] = v.z;
    t[rr][c0 + 3] = v.w;
    __syncthreads();
    int f = tid >> 4, jl = (tid & 15) * 4;
    ushort4 o;
    o.x = (unsigned short)(pkbf(t[jl + 0][f], 0.f) & 0xffff);
    o.y = (unsigned short)(pkbf(t[jl + 1][f], 0.f) & 0xffff);
    o.z = (unsigned short)(pkbf(t[jl + 2][f], 0.f) & 0xffff);
    o.w = (unsigned short)(pkbf(t[jl + 3][f], 0.f) & 0xffff);
    *(ushort4*)&dst[(size_t)(f0 + f) * M + j0 + jl] = o;
}

// ---------------- f1/f2 + softmax factor tables from WhT (bf16, coalesced) ----------------
__global__ __launch_bounds__(256) void fvec_k(const __hip_bfloat16* __restrict__ WhT,
                                              const float* __restrict__ a,
                                              float* __restrict__ f1, float* __restrict__ f2,
                                              float2* __restrict__ pns,
                                              int M, int D, long long sWh, long long sa) {
    int zz = blockIdx.y;
    const __hip_bfloat16* W = WhT + (long long)zz * sWh;
    const float* az = a + (long long)zz * sa;
    int i = blockIdx.x * 256 + threadIdx.x;
    float s1 = 0.f, s2 = 0.f;
    for (int k = 0; k < D; k++) {
        float ww = __bfloat162float(W[(size_t)k * M + i]);
        s1 = fmaf(ww, az[k], s1);
        s2 = fmaf(ww, az[D + k], s2);
    }
    f1[(size_t)zz * M + i] = s1;
    f2[(size_t)zz * M + i] = s2;
    pns[(size_t)zz * M + i] = make_float2(exp2f(L2E * s2), exp2f(L2E * 0.2f * s2));
}

// ---------------- per-batch max of f2 ----------------
__global__ __launch_bounds__(256) void rmax_k(const float* __restrict__ f2,
                                              float* __restrict__ out, int M, long long s) {
    int zz = blockIdx.x;
    const float* p = f2 + (long long)zz * s;
    float m = -1e30f;
    for (int t = threadIdx.x; t < M; t += 256) m = fmaxf(m, p[t]);
    __shared__ float red[256];
    red[threadIdx.x] = m;
    __syncthreads();
    for (int off = 128; off > 0; off >>= 1) {
        if (threadIdx.x < off) red[threadIdx.x] = fmaxf(red[threadIdx.x], red[threadIdx.x + off]);
        __syncthreads();
    }
    if (threadIdx.x == 0) out[zz] = red[0];
}

// ---------------- MFMA masked-softmax attention aggregation ----------------
// P[64 x 128] computed on VALU (exact hoisted-exp trick), bf16-packed into swizzled LDS;
// B tile = WhT[FOUT][128j] staged via global_load_lds with XOR-swizzled per-lane SOURCE;
// D = P @ WhT' accumulated by mfma_f32_16x16x32_bf16. Z via per-thread sums + LDS reduce.
// MODE 0: full-j per head, writes elu(out/Z) into hc[i][head*64+f].
// MODE 1: j-chunk partial (blockIdx.y = chunk), writes unnormalized part + Z.
template <int FOUT, int MODE>
__global__ __launch_bounds__(256) void attnm_k(const __hip_bfloat16* __restrict__ WhTB,
                                               const float* __restrict__ f1B,
                                               const float2* __restrict__ pnsB,
                                               const float* __restrict__ M2B,
                                               const unsigned int* __restrict__ mask32,
                                               float* __restrict__ outB,
                                               float* __restrict__ ZB,
                                               int jch) {
    constexpr int NN = 4096, TJ = 128;
    constexpr int MF = (FOUT == 64) ? 2 : 1;
    constexpr int NF = (FOUT == 64) ? 2 : 1;
    const int tid = threadIdx.x;
    const int lane = tid & 63;
    const int wv = tid >> 6;
    const int i0 = blockIdx.x * 64;

    const __hip_bfloat16* wt = WhTB;
    const float* f1p = f1B;
    const float2* pnp = pnsB;
    int head = 0, jlo = 0, jhi = NN, chunk = 0;
    float M2;
    if constexpr (MODE == 0) {
        head = blockIdx.y;
        wt += (size_t)head * FOUT * NN;
        f1p += (size_t)head * NN;
        pnp += (size_t)head * NN;
        M2 = M2B[head];
    } else {
        chunk = blockIdx.y;
        jlo = chunk * jch;
        jhi = jlo + jch;
        M2 = M2B[0];
    }

    __shared__ __align__(16) __hip_bfloat16 Bs[2][FOUT][TJ];
    __shared__ __align__(16) __hip_bfloat16 Ps[64][TJ];
    __shared__ __align__(16) float2 pns_s[2][TJ];
    __shared__ float Zs[64][4];
    __shared__ float Zrow[64];

    const int r = lane, jg = wv;
    float f1i = f1p[i0 + r];
    float t0 = f1i + M2;
    float m = fmaxf(t0, 0.2f * t0);            // lrelu upper bound of row max (exact softmax)
    float Pp = exp2f(L2E * (f1i - m));
    float Nn = exp2f(L2E * (0.2f * f1i - m));
    float T = exp2f(-L2E * f1i);
    float Z = 0.f;

    float4v acc[MF][NF];
#pragma unroll
    for (int a_ = 0; a_ < MF; a_++)
#pragma unroll
        for (int b_ = 0; b_ < NF; b_++) acc[a_][b_] = (float4v){0.f, 0.f, 0.f, 0.f};

    constexpr int CALLS = (FOUT * TJ * 2) / 4096;  // 1KB global_load_lds calls per wave
    auto stage = [&](int jt, int b) {
#pragma unroll
        for (int c = 0; c < CALLS; ++c) {
            int off = (wv * CALLS + c) * 1024 + lane * 16;
            int f = off >> 8;                 // LDS row (feature)
            int jb = (off >> 4) & 15;         // 16B block within row
            int jbs = jb ^ (f & 7);           // inverse-swizzled SOURCE block
            gld16((char*)&Bs[b][0][0] + (size_t)(wv * CALLS + c) * 1024,
                  wt + (size_t)f * NN + jt + jbs * 8);
        }
    };

    const int ntiles = (jhi - jlo) / TJ;
    stage(jlo, 0);
    if (tid < TJ) pns_s[0][tid] = pnp[jlo + tid];
    __syncthreads();

    const int rowb = (FOUT == 64) ? (wv & 1) * 32 : wv * 16;
    const int colb = (FOUT == 64) ? (wv >> 1) * 32 : 0;
    const int l16 = lane & 15;
    const int swzP = (r & 7) << 4;

    for (int t = 0; t < ntiles; ++t) {
        int jt = jlo + t * TJ;
        int cur = t & 1;
        if (t + 1 < ntiles) stage(jt + TJ, cur ^ 1);
        float2 pnreg;
        bool hn = (t + 1 < ntiles) && (tid < TJ);
        if (hn) pnreg = pnp[jt + TJ + tid];

        unsigned int mw = mask32[(size_t)(i0 + r) * (NN / 32) + (jt >> 5) + jg];
        const float2* pp = &pns_s[cur][jg * 32];
#pragma unroll
        for (int b = 0; b < 4; ++b) {
            float w[8];
#pragma unroll
            for (int e = 0; e < 8; ++e) {
                float2 pn = pp[b * 8 + e];
                float ww = (pn.x > T) ? Pp * pn.x : Nn * pn.y;
                ww = (mw & (1u << (b * 8 + e))) ? ww : 0.f;
                Z += ww;
                w[e] = ww;
            }
            uint4 pkv;
            pkv.x = pkbf(w[0], w[1]);
            pkv.y = pkbf(w[2], w[3]);
            pkv.z = pkbf(w[4], w[5]);
            pkv.w = pkbf(w[6], w[7]);
            *(uint4*)((char*)&Ps[0][0] + r * 256 + ((jg * 64 + b * 16) ^ swzP)) = pkv;
        }
        if (hn) pns_s[cur ^ 1][tid] = pnreg;
        __syncthreads();

        const char* psb = (const char*)&Ps[0][0];
        const char* bsb = (const char*)&Bs[cur][0][0];
#pragma unroll
        for (int kt = 0; kt < 4; ++kt) {
            int kb = kt * 64 + (lane >> 4) * 16;   // byte offset of the lane's 8 bf16 k-chunk
            short8v afr[MF], bfr[NF];
#pragma unroll
            for (int mf = 0; mf < MF; ++mf) {
                int row = rowb + mf * 16 + l16;
                afr[mf] = *(const short8v*)(psb + row * 256 + (kb ^ ((row & 7) << 4)));
            }
#pragma unroll
            for (int nf = 0; nf < NF; ++nf) {
                int col = colb + nf * 16 + l16;
                bfr[nf] = *(const short8v*)(bsb + col * 256 + (kb ^ ((col & 7) << 4)));
            }
#pragma unroll
            for (int mf = 0; mf < MF; ++mf)
#pragma unroll
                for (int nf = 0; nf < NF; ++nf)
                    acc[mf][nf] = __builtin_amdgcn_mfma_f32_16x16x32_bf16(
                        afr[mf], bfr[nf], acc[mf][nf], 0, 0, 0);
        }
        __syncthreads();
    }

    Zs[r][jg] = Z;
    __syncthreads();
    if (tid < 64) {
        float zs = Zs[tid][0] + Zs[tid][1] + Zs[tid][2] + Zs[tid][3];
        Zrow[tid] = zs;
        if constexpr (MODE == 1) ZB[(size_t)chunk * NN + i0 + tid] = zs;
    }
    __syncthreads();

#pragma unroll
    for (int mf = 0; mf < MF; ++mf)
#pragma unroll
        for (int nf = 0; nf < NF; ++nf) {
            int row0 = rowb + mf * 16 + (lane >> 4) * 4;
            int col = colb + nf * 16 + l16;
#pragma unroll
            for (int e = 0; e < 4; ++e) {
                float v = acc[mf][nf][e];
                int row = row0 + e;
                if constexpr (MODE == 0) {
                    float o = v / Zrow[row];
                    o = (o > 0.f) ? o : (__expf(o) - 1.f);
                    outB[(size_t)(i0 + row) * 512 + head * 64 + col] = o;
                } else {
                    outB[((size_t)chunk * NN + i0 + row) * FOUT + col] = v;
                }
            }
        }
}

// ---------------- combine j-split partials ----------------
__global__ __launch_bounds__(256) void comb2_k(const float* __restrict__ part,
                                               const float* __restrict__ Zp,
                                               const float* __restrict__ orig,
                                               float* __restrict__ zout, int N) {
    int id = blockIdx.x * 256 + threadIdx.x;  // N*64
    int i = id >> 6, f = id & 63;
    float Zs = 0.f, s = 0.f;
#pragma unroll
    for (int c = 0; c < 8; c++) Zs += Zp[(size_t)c * N + i];
#pragma unroll
    for (int c = 0; c < 8; c++) s += part[((size_t)c * N + i) * 64 + f];
    zout[id] = s / Zs + orig[id];
}

__global__ __launch_bounds__(256) void comb1_k(const float* __restrict__ part,
                                               const float* __restrict__ Zp,
                                               float* __restrict__ cls, int N) {
    int id = blockIdx.x * 256 + threadIdx.x;  // N*16
    int i = id >> 4, f = id & 15;
    float Zs = 0.f, s = 0.f;
#pragma unroll
    for (int c = 0; c < 8; c++) Zs += Zp[(size_t)c * N + i];
#pragma unroll
    for (int c = 0; c < 8; c++) s += part[((size_t)c * N + i) * 16 + f];
    float o = s / Zs;
    cls[id] = (o > 0.f) ? o : (expf(o) - 1.f);
}

// ---------------- log_softmax over 16 classes ----------------
__global__ __launch_bounds__(256) void lsm_k(const float* __restrict__ cls,
                                             float* __restrict__ out, int N) {
    int i = blockIdx.x * 256 + threadIdx.x;
    if (i >= N) return;
    float v[16];
    float m = -1e30f;
#pragma unroll
    for (int k = 0; k < 16; k++) {
        v[k] = cls[(size_t)i * 16 + k];
        m = fmaxf(m, v[k]);
    }
    float s = 0.f;
#pragma unroll
    for (int k = 0; k < 16; k++) s += expf(v[k] - m);
    float l = m + logf(s);
#pragma unroll
    for (int k = 0; k < 16; k++) out[(size_t)i * 16 + k] = v[k] - l;
}

// ---------------- result2 = z @ w_deg + b_deg ----------------
__global__ __launch_bounds__(256) void r2_k(const float* __restrict__ z,
                                            const float* __restrict__ wd,
                                            const float* __restrict__ bd,
                                            float* __restrict__ out, int N) {
    int i = blockIdx.x * 256 + threadIdx.x;
    if (i >= N) return;
    float s = bd[0];
#pragma unroll
    for (int k = 0; k < 64; k++) s = fmaf(z[(size_t)i * 64 + k], wd[k], s);
    out[i] = s;
}

extern "C" void kernel_launch(void* const* d_in, const int* in_sizes, int n_in,
                              void* d_out, int out_size, void* d_ws, size_t ws_size,
                              hipStream_t stream) {
    const float* x = (const float*)d_in[0];
    const int* adj = (const int*)d_in[1];
    const float* W_att = (const float*)d_in[2];
    const float* a_att = (const float*)d_in[3];
    const float* W_out1 = (const float*)d_in[4];
    const float* a_out1 = (const float*)d_in[5];
    const float* W_out2 = (const float*)d_in[6];
    const float* a_out2 = (const float*)d_in[7];
    const float* W_down = (const float*)d_in[8];
    const float* b_down = (const float*)d_in[9];
    const float* w_deg = (const float*)d_in[10];
    const float* b_deg = (const float*)d_in[11];
    const float* W_deg3 = (const float*)d_in[12];
    const float* b_deg3 = (const float*)d_in[13];
    float* out = (float*)d_out;

    constexpr int N = 4096, NF = 512, NH = 64, NC = 16, H = 8, DM = 128;

    char* wp = (char*)d_ws;
    auto alloc = [&](size_t b) {
        char* p = wp;
        wp += (b + 255) & ~(size_t)255;
        return p;
    };
    unsigned long long* mask = (unsigned long long*)alloc((size_t)N * N / 8);
    float* Wh = (float*)alloc((size_t)H * N * NH * 4);
    unsigned short* WhT = (unsigned short*)alloc((size_t)H * N * NH * 2);
    float* f1h = (float*)alloc((size_t)H * N * 4);
    float* f2h = (float*)alloc((size_t)H * N * 4);
    float2* pns_h = (float2*)alloc((size_t)H * N * 8);
    float* M2 = (float*)alloc(256);
    float* hc = (float*)alloc((size_t)N * NF * 4);
    float* orig = (float*)alloc((size_t)N * NH * 4);
    float* Wh1 = (float*)alloc((size_t)N * NC * 4);
    float* Wh2 = (float*)alloc((size_t)N * NH * 4);
    unsigned short* Wh1T = (unsigned short*)alloc((size_t)N * NC * 2);
    unsigned short* Wh2T = (unsigned short*)alloc((size_t)N * NH * 2);
    float* f1o1 = (float*)alloc((size_t)N * 4);
    float* f2o1 = (float*)alloc((size_t)N * 4);
    float* f1o2 = (float*)alloc((size_t)N * 4);
    float* f2o2 = (float*)alloc((size_t)N * 4);
    float2* pns_o1 = (float2*)alloc((size_t)N * 8);
    float2* pns_o2 = (float2*)alloc((size_t)N * 8);
    float* part1 = (float*)alloc((size_t)8 * N * NC * 4);
    float* Z1 = (float*)alloc((size_t)8 * N * 4);
    float* part2 = (float*)alloc((size_t)8 * N * NH * 4);
    float* Z2 = (float*)alloc((size_t)8 * N * 4);
    float* zbuf = (float*)alloc((size_t)N * NH * 4);
    float* cls = (float*)alloc((size_t)N * NC * 4);

    const unsigned int* mask32 = (const unsigned int*)mask;

    // 1. pack adjacency bitmask (2 MB, L2-resident)
    pack_k<<<(size_t)N * N / 256, 256, 0, stream>>>(adj, mask);
    // 2. Wh[h] = x @ W_att[h]; orig = x @ W_down + b_down
    gemm_k<<<dim3(N / 64, 1, H), 256, 0, stream>>>(x, W_att, nullptr, Wh, N, NH, NF,
                                                   (long long)NF * NH, (long long)N * NH);
    gemm_k<<<dim3(N / 64, 1, 1), 256, 0, stream>>>(x, W_down, b_down, orig, N, NH, NF, 0, 0);
    // 3. transpose+bf16: WhT[h][64][4096]
    tpose_k<<<dim3(N / 64, NH / 16, H), 256, 0, stream>>>(Wh, WhT, N, NH);
    // 4. f1/f2/pns per head + per-head max(f2)
    fvec_k<<<dim3(N / 256, H), 256, 0, stream>>>((const __hip_bfloat16*)WhT, a_att, f1h, f2h,
                                                 pns_h, N, NH, (long long)N * NH, 2 * NH);
    rmax_k<<<H, 256, 0, stream>>>(f2h, M2, N, N);
    // 5. 8-head MFMA attention -> hc (elu applied)
    attnm_k<64, 0><<<dim3(N / 64, H), 256, 0, stream>>>((const __hip_bfloat16*)WhT, f1h, pns_h,
                                                        M2, mask32, hc, nullptr, 0);
    // 6. second-layer projections + transposes + f-vectors
    gemm_k<<<dim3(N / 64, 1, 1), 256, 0, stream>>>(hc, W_out2, nullptr, Wh2, N, NH, NF, 0, 0);
    gemm_k<<<dim3(N / 64, 1, 1), 256, 0, stream>>>(hc, W_out1, nullptr, Wh1, N, NC, NF, 0, 0);
    tpose_k<<<dim3(N / 64, NH / 16, 1), 256, 0, stream>>>(Wh2, Wh2T, N, NH);
    tpose_k<<<dim3(N / 64, NC / 16, 1), 256, 0, stream>>>(Wh1, Wh1T, N, NC);
    fvec_k<<<dim3(N / 256, 1), 256, 0, stream>>>((const __hip_bfloat16*)Wh2T, a_out2, f1o2, f2o2,
                                                 pns_o2, N, NH, 0, 0);
    fvec_k<<<dim3(N / 256, 1), 256, 0, stream>>>((const __hip_bfloat16*)Wh1T, a_out1, f1o1, f2o1,
                                                 pns_o1, N, NC, 0, 0);
    rmax_k<<<1, 256, 0, stream>>>(f2o1, M2 + 8, N, 0);
    rmax_k<<<1, 256, 0, stream>>>(f2o2, M2 + 9, N, 0);
    // 7. out2/out1 MFMA attention, 8-way j-split (shared row-max -> additive combine)
    attnm_k<64, 1><<<dim3(N / 64, 8), 256, 0, stream>>>((const __hip_bfloat16*)Wh2T, f1o2,
                                                        pns_o2, M2 + 9, mask32, part2, Z2, 512);
    attnm_k<16, 1><<<dim3(N / 64, 8), 256, 0, stream>>>((const __hip_bfloat16*)Wh1T, f1o1,
                                                        pns_o1, M2 + 8, mask32, part1, Z1, 512);
    comb2_k<<<(size_t)N * 64 / 256, 256, 0, stream>>>(part2, Z2, orig, zbuf, N);
    comb1_k<<<(size_t)N * 16 / 256, 256, 0, stream>>>(part1, Z1, cls, N);
    // 8. outputs
    lsm_k<<<N / 256, 256, 0, stream>>>(cls, out, N);
    r2_k<<<N / 256, 256, 0, stream>>>(zbuf, w_deg, b_deg, out + (size_t)N * NC, N);
    gemm_k<<<dim3(N / 64, 2, 1), 256, 0, stream>>>(zbuf, W_deg3, b_deg3,
                                                   out + (size_t)N * NC + N, N, DM, NH, 0, 0);
}

// Round 4
// 376.405 us; speedup vs baseline: 4.0894x; 1.8174x over previous
//
#include <hip/hip_runtime.h>
#include <hip/hip_bf16.h>

#define L2E 1.44269504088896f

typedef __attribute__((ext_vector_type(8))) short short8v;
typedef __attribute__((ext_vector_type(4))) float float4v;

__device__ __forceinline__ void gld16(void* lds, const void* gp) {
    __builtin_amdgcn_global_load_lds(
        (const __attribute__((address_space(1))) unsigned int*)gp,
        (__attribute__((address_space(3))) unsigned int*)lds, 16, 0, 0);
}

__device__ __forceinline__ unsigned int pkbf(float a, float b) {
    unsigned int r;
    asm("v_cvt_pk_bf16_f32 %0, %1, %2" : "=v"(r) : "v"(a), "v"(b));
    return r;
}

// ---------------- pack adj -> bitmask ----------------
__global__ __launch_bounds__(256) void pack_k(const int* __restrict__ adj,
                                              unsigned long long* __restrict__ mask) {
    size_t idx = (size_t)blockIdx.x * 256 + threadIdx.x;
    int v = adj[idx];
    unsigned long long b = __ballot(v > 0);
    if ((threadIdx.x & 63) == 0) mask[idx >> 6] = b;
}

// ---------------- f32 -> bf16 bulk convert (8 elems/thread) ----------------
__global__ __launch_bounds__(256) void cvt_k(const float* __restrict__ src,
                                             unsigned short* __restrict__ dst, int n8) {
    int i = blockIdx.x * 256 + threadIdx.x;
    if (i >= n8) return;
    float4 a = ((const float4*)src)[i * 2];
    float4 b = ((const float4*)src)[i * 2 + 1];
    uint4 o;
    o.x = pkbf(a.x, a.y);
    o.y = pkbf(a.z, a.w);
    o.z = pkbf(b.x, b.y);
    o.w = pkbf(b.z, b.w);
    ((uint4*)dst)[i] = o;
}

// ---------------- batched transpose + bf16: src [M][F] f32 -> dst [F][M] bf16 ----------
__global__ __launch_bounds__(256) void tpose_k(const float* __restrict__ src,
                                               unsigned short* __restrict__ dst,
                                               int M, int F) {
    src += (size_t)blockIdx.z * M * F;
    dst += (size_t)blockIdx.z * F * M;
    __shared__ float t[64][17];
    int j0 = blockIdx.x * 64, f0 = blockIdx.y * 16;
    int tid = threadIdx.x;
    int rr = tid >> 2, c0 = (tid & 3) * 4;
    float4 v = *(const float4*)&src[(size_t)(j0 + rr) * F + f0 + c0];
    t[rr][c0 + 0] = v.x;
    t[rr][c0 + 1] = v.y;
    t[rr][c0 + 2] = v.z;
    t[rr][c0 + 3] = v.w;
    __syncthreads();
    int f = tid >> 4, jl = (tid & 15) * 4;
    ushort4 o;
    o.x = (unsigned short)(pkbf(t[jl + 0][f], 0.f) & 0xffff);
    o.y = (unsigned short)(pkbf(t[jl + 1][f], 0.f) & 0xffff);
    o.z = (unsigned short)(pkbf(t[jl + 2][f], 0.f) & 0xffff);
    o.w = (unsigned short)(pkbf(t[jl + 3][f], 0.f) & 0xffff);
    *(ushort4*)&dst[(size_t)(f0 + f) * M + j0 + jl] = o;
}

// ---------------- bf16 MFMA GEMM: C = A[MxK] @ Bt[NxK]^T ----------------
// OUTMODE 0: C f32 [Z][M][N] (+bias);  OUTMODE 1: C bf16 [Z][N][M] (transposed)
template <int BN, int OUTMODE>
__global__ __launch_bounds__(256) void gemmb_k(const __hip_bfloat16* __restrict__ A,
                                               const __hip_bfloat16* __restrict__ BtB,
                                               const float* __restrict__ bias,
                                               void* __restrict__ CB,
                                               int M, int N, int K) {
    constexpr int BM = 128, BK = 64;
    const int tid = threadIdx.x, lane = tid & 63, wv = tid >> 6;
    const int l16 = lane & 15, kq = lane >> 4;
    const int row0 = blockIdx.x * BM, col0 = blockIdx.y * BN;
    const size_t czs = (size_t)M * N;
    const __hip_bfloat16* Bt = BtB + (size_t)blockIdx.z * N * K;

    __shared__ __align__(16) __hip_bfloat16 As[2][BM][BK];  // 16 KB x2, XOR-swizzled

    auto stageA = [&](int k0, int b) {
#pragma unroll
        for (int c = 0; c < 4; ++c) {
            int off = (tid + c * 256) * 16;
            int rr = off >> 7;             // LDS row (128B rows)
            int ch = (off >> 4) & 7;       // 16B chunk
            int chs = ch ^ (rr & 7);       // inverse-swizzled source chunk
            gld16((char*)&As[b][0][0] + off, A + (size_t)(row0 + rr) * K + k0 + chs * 8);
        }
    };

    float4v acc[2][BN / 16];
#pragma unroll
    for (int mf = 0; mf < 2; ++mf)
#pragma unroll
        for (int nf = 0; nf < BN / 16; ++nf) acc[mf][nf] = (float4v){0.f, 0.f, 0.f, 0.f};

    const int nk = K / BK;
    stageA(0, 0);
    for (int t = 0; t < nk; ++t) {
        int k0 = t * BK, cur = t & 1;
        if (t + 1 < nk) stageA(k0 + BK, cur ^ 1);
        short8v bfr[BN / 16][2];
#pragma unroll
        for (int nf = 0; nf < BN / 16; ++nf)
#pragma unroll
            for (int ks = 0; ks < 2; ++ks)
                bfr[nf][ks] = *(const short8v*)(Bt + (size_t)(col0 + nf * 16 + l16) * K +
                                                k0 + ks * 32 + kq * 8);
        __syncthreads();
        const char* asb = (const char*)&As[cur][0][0];
#pragma unroll
        for (int ks = 0; ks < 2; ++ks) {
            short8v afr[2];
#pragma unroll
            for (int mf = 0; mf < 2; ++mf) {
                int rr = wv * 32 + mf * 16 + l16;
                afr[mf] = *(const short8v*)(asb + rr * 128 +
                                            ((ks * 64 + kq * 16) ^ ((rr & 7) << 4)));
            }
#pragma unroll
            for (int mf = 0; mf < 2; ++mf)
#pragma unroll
                for (int nf = 0; nf < BN / 16; ++nf)
                    acc[mf][nf] = __builtin_amdgcn_mfma_f32_16x16x32_bf16(
                        afr[mf], bfr[nf][ks], acc[mf][nf], 0, 0, 0);
        }
        __syncthreads();
    }

#pragma unroll
    for (int mf = 0; mf < 2; ++mf)
#pragma unroll
        for (int nf = 0; nf < BN / 16; ++nf) {
            int rb = row0 + wv * 32 + mf * 16 + kq * 4;
            int col = col0 + nf * 16 + l16;
            if constexpr (OUTMODE == 0) {
                float bb = bias ? bias[col] : 0.f;
                float* C = (float*)CB + (size_t)blockIdx.z * czs;
#pragma unroll
                for (int e = 0; e < 4; ++e) C[(size_t)(rb + e) * N + col] = acc[mf][nf][e] + bb;
            } else {
                ushort4 u;
                u.x = (unsigned short)(pkbf(acc[mf][nf][0], 0.f) & 0xffff);
                u.y = (unsigned short)(pkbf(acc[mf][nf][1], 0.f) & 0xffff);
                u.z = (unsigned short)(pkbf(acc[mf][nf][2], 0.f) & 0xffff);
                u.w = (unsigned short)(pkbf(acc[mf][nf][3], 0.f) & 0xffff);
                unsigned short* Ct = (unsigned short*)CB + (size_t)blockIdx.z * czs;
                *(ushort4*)&Ct[(size_t)col * M + rb] = u;
            }
        }
}

// ---------------- f1/f2 + softmax factor tables from WhT (bf16, coalesced) ----------------
__global__ __launch_bounds__(256) void fvec_k(const __hip_bfloat16* __restrict__ WhT,
                                              const float* __restrict__ a,
                                              float* __restrict__ f1, float* __restrict__ f2,
                                              float2* __restrict__ pns,
                                              int M, int D, long long sWh, long long sa) {
    int zz = blockIdx.y;
    const __hip_bfloat16* W = WhT + (long long)zz * sWh;
    const float* az = a + (long long)zz * sa;
    int i = blockIdx.x * 256 + threadIdx.x;
    float s1 = 0.f, s2 = 0.f;
    for (int k = 0; k < D; k++) {
        float ww = __bfloat162float(W[(size_t)k * M + i]);
        s1 = fmaf(ww, az[k], s1);
        s2 = fmaf(ww, az[D + k], s2);
    }
    f1[(size_t)zz * M + i] = s1;
    f2[(size_t)zz * M + i] = s2;
    pns[(size_t)zz * M + i] = make_float2(exp2f(L2E * s2), exp2f(L2E * 0.2f * s2));
}

// ---------------- per-batch max of f2 ----------------
__global__ __launch_bounds__(256) void rmax_k(const float* __restrict__ f2,
                                              float* __restrict__ out, int M, long long s) {
    int zz = blockIdx.x;
    const float* p = f2 + (long long)zz * s;
    float m = -1e30f;
    for (int t = threadIdx.x; t < M; t += 256) m = fmaxf(m, p[t]);
    __shared__ float red[256];
    red[threadIdx.x] = m;
    __syncthreads();
    for (int off = 128; off > 0; off >>= 1) {
        if (threadIdx.x < off) red[threadIdx.x] = fmaxf(red[threadIdx.x], red[threadIdx.x + off]);
        __syncthreads();
    }
    if (threadIdx.x == 0) out[zz] = red[0];
}

// ---------------- MFMA masked-softmax attention aggregation ----------------
// P on VALU (w = max(Pp*e^{f2}, Nn*e^{0.2 f2}) — exact lrelu-exp identity), bf16 into
// double-buffered swizzled Ps (ONE barrier/tile); B-frags straight from L2 (WhT rows);
// pn factors via wave-uniform scalar loads. MODE 0: writes elu(out/Z) as bf16 hc.
// MODE 1: j-chunk partials (f32) + Z.
template <int FOUT, int MODE>
__global__ __launch_bounds__(256) void attnm_k(const __hip_bfloat16* __restrict__ WhTB,
                                               const float* __restrict__ f1B,
                                               const float2* __restrict__ pnsB,
                                               const float* __restrict__ M2B,
                                               const unsigned int* __restrict__ mask32,
                                               void* __restrict__ outB,
                                               float* __restrict__ ZB,
                                               int jch) {
    constexpr int NN = 4096, TJ = 128;
    constexpr int MF = (FOUT == 64) ? 2 : 1;
    constexpr int NF = (FOUT == 64) ? 2 : 1;
    const int tid = threadIdx.x;
    const int lane = tid & 63;
    const int wv = tid >> 6;
    const int jg = __builtin_amdgcn_readfirstlane(wv);
    const int i0 = blockIdx.x * 64;
    const int l16 = lane & 15, kq = lane >> 4;
    const int r = lane;

    const __hip_bfloat16* wt = WhTB;
    const float* f1p = f1B;
    const float2* pnp = pnsB;
    int head = 0, jlo = 0, nt, chunk = 0;
    float M2;
    if constexpr (MODE == 0) {
        head = blockIdx.y;
        wt += (size_t)head * FOUT * NN;
        f1p += (size_t)head * NN;
        pnp += (size_t)head * NN;
        M2 = M2B[head];
        nt = NN / TJ;
    } else {
        chunk = blockIdx.y;
        jlo = chunk * jch;
        nt = jch / TJ;
        M2 = M2B[0];
    }

    __shared__ __align__(16) __hip_bfloat16 Ps[2][64][TJ];
    __shared__ float Zs[64][4];
    __shared__ float Zrow[64];

    float f1i = f1p[i0 + r];
    float t0 = f1i + M2;
    float m = fmaxf(t0, 0.2f * t0);          // lrelu upper bound of row max (exact softmax)
    float Pp = exp2f(L2E * (f1i - m));
    float Nn = exp2f(L2E * (0.2f * f1i - m));
    float Z = 0.f;

    float4v acc[MF][NF];
#pragma unroll
    for (int mf = 0; mf < MF; ++mf)
#pragma unroll
        for (int nf = 0; nf < NF; ++nf) acc[mf][nf] = (float4v){0.f, 0.f, 0.f, 0.f};

    const int rowb = (FOUT == 64) ? (wv & 1) * 32 : wv * 16;
    const int colb = (FOUT == 64) ? (wv >> 1) * 32 : 0;
    const int swzP = (r & 7) << 4;
    const unsigned int* mrowp = mask32 + (size_t)(i0 + r) * (NN >> 5) + jg;
    char* psbase = (char*)&Ps[0][0][0];

    auto pcompute = [&](int jt, int buf, unsigned int mw) {
        const float2* pw = pnp + jt + jg * 32;   // wave-uniform -> s_load
        char* pd = psbase + buf * (64 * TJ * 2) + r * 256;
#pragma unroll
        for (int b = 0; b < 4; ++b) {
            float w[8];
#pragma unroll
            for (int e = 0; e < 8; ++e) {
                float2 pn = pw[b * 8 + e];
                float ww = fmaxf(Pp * pn.x, Nn * pn.y);
                ww = (mw & (1u << (b * 8 + e))) ? ww : 0.f;
                Z += ww;
                w[e] = ww;
            }
            uint4 pkv;
            pkv.x = pkbf(w[0], w[1]);
            pkv.y = pkbf(w[2], w[3]);
            pkv.z = pkbf(w[4], w[5]);
            pkv.w = pkbf(w[6], w[7]);
            *(uint4*)(pd + ((jg * 64 + b * 16) ^ swzP)) = pkv;
        }
    };

    pcompute(jlo, 0, mrowp[jlo >> 5]);

    for (int t = 0; t < nt; ++t) {
        int jt = jlo + t * TJ;
        __syncthreads();                         // Ps[t&1] ready for all waves
        short8v bfr[4][NF];                      // B-frags for tile t, straight from L2
#pragma unroll
        for (int kt = 0; kt < 4; ++kt)
#pragma unroll
            for (int nf = 0; nf < NF; ++nf)
                bfr[kt][nf] = *(const short8v*)(wt + (size_t)(colb + nf * 16 + l16) * NN +
                                                jt + kt * 32 + kq * 8);
        if (t + 1 < nt) pcompute(jt + TJ, (t + 1) & 1, mrowp[(jt + TJ) >> 5]);
        const char* psb = psbase + (t & 1) * (64 * TJ * 2);
#pragma unroll
        for (int kt = 0; kt < 4; ++kt) {
            short8v afr[MF];
#pragma unroll
            for (int mf = 0; mf < MF; ++mf) {
                int row = rowb + mf * 16 + l16;
                afr[mf] = *(const short8v*)(psb + row * 256 +
                                            ((kt * 64 + kq * 16) ^ ((row & 7) << 4)));
            }
#pragma unroll
            for (int mf = 0; mf < MF; ++mf)
#pragma unroll
                for (int nf = 0; nf < NF; ++nf)
                    acc[mf][nf] = __builtin_amdgcn_mfma_f32_16x16x32_bf16(
                        afr[mf], bfr[kt][nf], acc[mf][nf], 0, 0, 0);
        }
    }

    Zs[r][wv] = Z;
    __syncthreads();
    if (tid < 64) {
        float zs = Zs[tid][0] + Zs[tid][1] + Zs[tid][2] + Zs[tid][3];
        Zrow[tid] = zs;
        if constexpr (MODE == 1) ZB[(size_t)chunk * NN + i0 + tid] = zs;
    }
    __syncthreads();

#pragma unroll
    for (int mf = 0; mf < MF; ++mf)
#pragma unroll
        for (int nf = 0; nf < NF; ++nf) {
            int rb = rowb + mf * 16 + kq * 4;
            int col = colb + nf * 16 + l16;
#pragma unroll
            for (int e = 0; e < 4; ++e) {
                float v = acc[mf][nf][e];
                int row = rb + e;
                if constexpr (MODE == 0) {
                    float o = v / Zrow[row];
                    o = (o > 0.f) ? o : (__expf(o) - 1.f);   // elu
                    ((unsigned short*)outB)[(size_t)(i0 + row) * 512 + head * 64 + col] =
                        (unsigned short)(pkbf(o, 0.f) & 0xffff);
                } else {
                    ((float*)outB)[((size_t)chunk * NN + i0 + row) * FOUT + col] = v;
                }
            }
        }
}

// ---------------- combine j-split partials ----------------
__global__ __launch_bounds__(256) void comb2_k(const float* __restrict__ part,
                                               const float* __restrict__ Zp,
                                               const float* __restrict__ orig,
                                               float* __restrict__ zout, int N) {
    int id = blockIdx.x * 256 + threadIdx.x;  // N*64
    int i = id >> 6, f = id & 63;
    float Zs = 0.f, s = 0.f;
#pragma unroll
    for (int c = 0; c < 8; c++) Zs += Zp[(size_t)c * N + i];
#pragma unroll
    for (int c = 0; c < 8; c++) s += part[((size_t)c * N + i) * 64 + f];
    zout[id] = s / Zs + orig[id];
}

__global__ __launch_bounds__(256) void comb1_k(const float* __restrict__ part,
                                               const float* __restrict__ Zp,
                                               float* __restrict__ cls, int N) {
    int id = blockIdx.x * 256 + threadIdx.x;  // N*16
    int i = id >> 4, f = id & 15;
    float Zs = 0.f, s = 0.f;
#pragma unroll
    for (int c = 0; c < 8; c++) Zs += Zp[(size_t)c * N + i];
#pragma unroll
    for (int c = 0; c < 8; c++) s += part[((size_t)c * N + i) * 16 + f];
    float o = s / Zs;
    cls[id] = (o > 0.f) ? o : (expf(o) - 1.f);
}

// ---------------- log_softmax over 16 classes ----------------
__global__ __launch_bounds__(256) void lsm_k(const float* __restrict__ cls,
                                             float* __restrict__ out, int N) {
    int i = blockIdx.x * 256 + threadIdx.x;
    if (i >= N) return;
    float v[16];
    float m = -1e30f;
#pragma unroll
    for (int k = 0; k < 16; k++) {
        v[k] = cls[(size_t)i * 16 + k];
        m = fmaxf(m, v[k]);
    }
    float s = 0.f;
#pragma unroll
    for (int k = 0; k < 16; k++) s += expf(v[k] - m);
    float l = m + logf(s);
#pragma unroll
    for (int k = 0; k < 16; k++) out[(size_t)i * 16 + k] = v[k] - l;
}

// ---------------- result2 = z @ w_deg + b_deg ----------------
__global__ __launch_bounds__(256) void r2_k(const float* __restrict__ z,
                                            const float* __restrict__ wd,
                                            const float* __restrict__ bd,
                                            float* __restrict__ out, int N) {
    int i = blockIdx.x * 256 + threadIdx.x;
    if (i >= N) return;
    float s = bd[0];
#pragma unroll
    for (int k = 0; k < 64; k++) s = fmaf(z[(size_t)i * 64 + k], wd[k], s);
    out[i] = s;
}

extern "C" void kernel_launch(void* const* d_in, const int* in_sizes, int n_in,
                              void* d_out, int out_size, void* d_ws, size_t ws_size,
                              hipStream_t stream) {
    const float* x = (const float*)d_in[0];
    const int* adj = (const int*)d_in[1];
    const float* W_att = (const float*)d_in[2];
    const float* a_att = (const float*)d_in[3];
    const float* W_out1 = (const float*)d_in[4];
    const float* a_out1 = (const float*)d_in[5];
    const float* W_out2 = (const float*)d_in[6];
    const float* a_out2 = (const float*)d_in[7];
    const float* W_down = (const float*)d_in[8];
    const float* b_down = (const float*)d_in[9];
    const float* w_deg = (const float*)d_in[10];
    const float* b_deg = (const float*)d_in[11];
    const float* W_deg3 = (const float*)d_in[12];
    const float* b_deg3 = (const float*)d_in[13];
    float* out = (float*)d_out;

    constexpr int N = 4096, NF = 512, NH = 64, NC = 16, H = 8, DM = 128;

    char* wp = (char*)d_ws;
    auto alloc = [&](size_t b) {
        char* p = wp;
        wp += (b + 255) & ~(size_t)255;
        return p;
    };
    unsigned long long* mask = (unsigned long long*)alloc((size_t)N * N / 8);
    unsigned short* xb = (unsigned short*)alloc((size_t)N * NF * 2);
    unsigned short* WbT = (unsigned short*)alloc((size_t)H * NH * NF * 2);
    unsigned short* WdT = (unsigned short*)alloc((size_t)NH * NF * 2);
    unsigned short* Wo2T = (unsigned short*)alloc((size_t)NH * NF * 2);
    unsigned short* Wo1T = (unsigned short*)alloc((size_t)NC * NF * 2);
    unsigned short* Wd3T = (unsigned short*)alloc((size_t)DM * NH * 2);
    unsigned short* WhT = (unsigned short*)alloc((size_t)H * NH * N * 2);
    float* f1h = (float*)alloc((size_t)H * N * 4);
    float* f2h = (float*)alloc((size_t)H * N * 4);
    float2* pns_h = (float2*)alloc((size_t)H * N * 8);
    float* M2 = (float*)alloc(256);
    unsigned short* hcb = (unsigned short*)alloc((size_t)N * NF * 2);
    float* orig = (float*)alloc((size_t)N * NH * 4);
    unsigned short* Wh1T = (unsigned short*)alloc((size_t)NC * N * 2);
    unsigned short* Wh2T = (unsigned short*)alloc((size_t)NH * N * 2);
    float* f1o1 = (float*)alloc((size_t)N * 4);
    float* f2o1 = (float*)alloc((size_t)N * 4);
    float* f1o2 = (float*)alloc((size_t)N * 4);
    float* f2o2 = (float*)alloc((size_t)N * 4);
    float2* pns_o1 = (float2*)alloc((size_t)N * 8);
    float2* pns_o2 = (float2*)alloc((size_t)N * 8);
    float* part1 = (float*)alloc((size_t)8 * N * NC * 4);
    float* Z1 = (float*)alloc((size_t)8 * N * 4);
    float* part2 = (float*)alloc((size_t)8 * N * NH * 4);
    float* Z2 = (float*)alloc((size_t)8 * N * 4);
    float* zbuf = (float*)alloc((size_t)N * NH * 4);
    unsigned short* zb = (unsigned short*)alloc((size_t)N * NH * 2);
    float* cls = (float*)alloc((size_t)N * NC * 4);

    const unsigned int* mask32 = (const unsigned int*)mask;

    // 1. pack adjacency bitmask; convert x to bf16; transpose all weights to [N][K] bf16
    pack_k<<<(size_t)N * N / 256, 256, 0, stream>>>(adj, mask);
    cvt_k<<<(N * NF / 8 + 255) / 256, 256, 0, stream>>>(x, xb, N * NF / 8);
    tpose_k<<<dim3(NF / 64, NH / 16, H), 256, 0, stream>>>(W_att, WbT, NF, NH);
    tpose_k<<<dim3(NF / 64, NH / 16, 1), 256, 0, stream>>>(W_down, WdT, NF, NH);
    tpose_k<<<dim3(NF / 64, NH / 16, 1), 256, 0, stream>>>(W_out2, Wo2T, NF, NH);
    tpose_k<<<dim3(NF / 64, NC / 16, 1), 256, 0, stream>>>(W_out1, Wo1T, NF, NC);
    tpose_k<<<dim3(1, DM / 16, 1), 256, 0, stream>>>(W_deg3, Wd3T, NH, DM);
    // 2. WhT[h] = (xb @ W_att[h])^T bf16 (direct transposed write); orig = x@W_down + b
    gemmb_k<64, 1><<<dim3(N / 128, 1, H), 256, 0, stream>>>(
        (const __hip_bfloat16*)xb, (const __hip_bfloat16*)WbT, nullptr, WhT, N, NH, NF);
    gemmb_k<64, 0><<<dim3(N / 128, 1, 1), 256, 0, stream>>>(
        (const __hip_bfloat16*)xb, (const __hip_bfloat16*)WdT, b_down, orig, N, NH, NF);
    // 3. f1/f2/pns per head + per-head max(f2)
    fvec_k<<<dim3(N / 256, H), 256, 0, stream>>>((const __hip_bfloat16*)WhT, a_att, f1h, f2h,
                                                 pns_h, N, NH, (long long)NH * N, 2 * NH);
    rmax_k<<<H, 256, 0, stream>>>(f2h, M2, N, N);
    // 4. 8-head MFMA attention -> hcb bf16 (elu applied)
    attnm_k<64, 0><<<dim3(N / 64, H), 256, 0, stream>>>((const __hip_bfloat16*)WhT, f1h, pns_h,
                                                        M2, mask32, hcb, nullptr, 0);
    // 5. second-layer projections (transposed bf16 outputs) + f-vectors
    gemmb_k<64, 1><<<dim3(N / 128, 1, 1), 256, 0, stream>>>(
        (const __hip_bfloat16*)hcb, (const __hip_bfloat16*)Wo2T, nullptr, Wh2T, N, NH, NF);
    gemmb_k<16, 1><<<dim3(N / 128, 1, 1), 256, 0, stream>>>(
        (const __hip_bfloat16*)hcb, (const __hip_bfloat16*)Wo1T, nullptr, Wh1T, N, NC, NF);
    fvec_k<<<dim3(N / 256, 1), 256, 0, stream>>>((const __hip_bfloat16*)Wh2T, a_out2, f1o2, f2o2,
                                                 pns_o2, N, NH, 0, 0);
    fvec_k<<<dim3(N / 256, 1), 256, 0, stream>>>((const __hip_bfloat16*)Wh1T, a_out1, f1o1, f2o1,
                                                 pns_o1, N, NC, 0, 0);
    rmax_k<<<1, 256, 0, stream>>>(f2o1, M2 + 8, N, 0);
    rmax_k<<<1, 256, 0, stream>>>(f2o2, M2 + 9, N, 0);
    // 6. out2/out1 MFMA attention, 8-way j-split (shared row-max -> additive combine)
    attnm_k<64, 1><<<dim3(N / 64, 8), 256, 0, stream>>>((const __hip_bfloat16*)Wh2T, f1o2,
                                                        pns_o2, M2 + 9, mask32, part2, Z2, 512);
    attnm_k<16, 1><<<dim3(N / 64, 8), 256, 0, stream>>>((const __hip_bfloat16*)Wh1T, f1o1,
                                                        pns_o1, M2 + 8, mask32, part1, Z1, 512);
    comb2_k<<<(size_t)N * 64 / 256, 256, 0, stream>>>(part2, Z2, orig, zbuf, N);
    comb1_k<<<(size_t)N * 16 / 256, 256, 0, stream>>>(part1, Z1, cls, N);
    // 7. outputs
    lsm_k<<<N / 256, 256, 0, stream>>>(cls, out, N);
    r2_k<<<N / 256, 256, 0, stream>>>(zbuf, w_deg, b_deg, out + (size_t)N * NC, N);
    cvt_k<<<(N * NH / 8 + 255) / 256, 256, 0, stream>>>(zbuf, zb, N * NH / 8);
    gemmb_k<64, 0><<<dim3(N / 128, DM / 64, 1), 256, 0, stream>>>(
        (const __hip_bfloat16*)zb, (const __hip_bfloat16*)Wd3T, b_deg3,
        out + (size_t)N * NC + N, N, DM, NH);
}

// Round 5
// 372.578 us; speedup vs baseline: 4.1314x; 1.0103x over previous
//
#include <hip/hip_runtime.h>
#include <hip/hip_bf16.h>

#define L2E 1.44269504088896f

typedef __attribute__((ext_vector_type(8))) short short8v;
typedef __attribute__((ext_vector_type(4))) float float4v;

__device__ __forceinline__ void gld16(void* lds, const void* gp) {
    __builtin_amdgcn_global_load_lds(
        (const __attribute__((address_space(1))) unsigned int*)gp,
        (__attribute__((address_space(3))) unsigned int*)lds, 16, 0, 0);
}

__device__ __forceinline__ unsigned int pkbf(float a, float b) {
    unsigned int r;
    asm("v_cvt_pk_bf16_f32 %0, %1, %2" : "=v"(r) : "v"(a), "v"(b));
    return r;
}

// ---------------- pack adj -> bitmask ----------------
__global__ __launch_bounds__(256) void pack_k(const int* __restrict__ adj,
                                              unsigned long long* __restrict__ mask) {
    size_t idx = (size_t)blockIdx.x * 256 + threadIdx.x;
    int v = adj[idx];
    unsigned long long b = __ballot(v > 0);
    if ((threadIdx.x & 63) == 0) mask[idx >> 6] = b;
}

// ---------------- f32 -> bf16 bulk convert (8 elems/thread) ----------------
__global__ __launch_bounds__(256) void cvt_k(const float* __restrict__ src,
                                             unsigned short* __restrict__ dst, int n8) {
    int i = blockIdx.x * 256 + threadIdx.x;
    if (i >= n8) return;
    float4 a = ((const float4*)src)[i * 2];
    float4 b = ((const float4*)src)[i * 2 + 1];
    uint4 o;
    o.x = pkbf(a.x, a.y);
    o.y = pkbf(a.z, a.w);
    o.z = pkbf(b.x, b.y);
    o.w = pkbf(b.z, b.w);
    ((uint4*)dst)[i] = o;
}

// ---------------- transpose + bf16: src [M][F] f32 -> dst [F][M] bf16 ----------
__global__ __launch_bounds__(256) void tpose_k(const float* __restrict__ src,
                                               unsigned short* __restrict__ dst,
                                               int M, int F) {
    src += (size_t)blockIdx.z * M * F;
    dst += (size_t)blockIdx.z * F * M;
    __shared__ float t[64][17];
    int j0 = blockIdx.x * 64, f0 = blockIdx.y * 16;
    int tid = threadIdx.x;
    int rr = tid >> 2, c0 = (tid & 3) * 4;
    float4 v = *(const float4*)&src[(size_t)(j0 + rr) * F + f0 + c0];
    t[rr][c0 + 0] = v.x;
    t[rr][c0 + 1] = v.y;
    t[rr][c0 + 2] = v.z;
    t[rr][c0 + 3] = v.w;
    __syncthreads();
    int f = tid >> 4, jl = (tid & 15) * 4;
    ushort4 o;
    o.x = (unsigned short)(pkbf(t[jl + 0][f], 0.f) & 0xffff);
    o.y = (unsigned short)(pkbf(t[jl + 1][f], 0.f) & 0xffff);
    o.z = (unsigned short)(pkbf(t[jl + 2][f], 0.f) & 0xffff);
    o.w = (unsigned short)(pkbf(t[jl + 3][f], 0.f) & 0xffff);
    *(ushort4*)&dst[(size_t)(f0 + f) * M + j0 + jl] = o;
}

// same, z-selected source (0..7 -> p0 batch, 8 -> p1, 9 -> p2), 512x64 each
__global__ __launch_bounds__(256) void tposeSel_k(const float* __restrict__ p0,
                                                  const float* __restrict__ p1,
                                                  const float* __restrict__ p2,
                                                  unsigned short* __restrict__ dst,
                                                  int M, int F) {
    int z = blockIdx.z;
    const float* src = (z < 8) ? p0 + (size_t)z * M * F : ((z == 8) ? p1 : p2);
    dst += (size_t)z * F * M;
    __shared__ float t[64][17];
    int j0 = blockIdx.x * 64, f0 = blockIdx.y * 16;
    int tid = threadIdx.x;
    int rr = tid >> 2, c0 = (tid & 3) * 4;
    float4 v = *(const float4*)&src[(size_t)(j0 + rr) * F + f0 + c0];
    t[rr][c0 + 0] = v.x;
    t[rr][c0 + 1] = v.y;
    t[rr][c0 + 2] = v.z;
    t[rr][c0 + 3] = v.w;
    __syncthreads();
    int f = tid >> 4, jl = (tid & 15) * 4;
    ushort4 o;
    o.x = (unsigned short)(pkbf(t[jl + 0][f], 0.f) & 0xffff);
    o.y = (unsigned short)(pkbf(t[jl + 1][f], 0.f) & 0xffff);
    o.z = (unsigned short)(pkbf(t[jl + 2][f], 0.f) & 0xffff);
    o.w = (unsigned short)(pkbf(t[jl + 3][f], 0.f) & 0xffff);
    *(ushort4*)&dst[(size_t)(f0 + f) * M + j0 + jl] = o;
}

// ---------------- bf16 MFMA GEMM: C = A[MxK] @ Bt[NxK]^T ----------------
// OUTMODE 0: C f32 [Z][M][N] (+bias);  OUTMODE 1: C bf16 [Z][N][M] (transposed)
template <int BN, int OUTMODE>
__global__ __launch_bounds__(256) void gemmb_k(const __hip_bfloat16* __restrict__ A,
                                               const __hip_bfloat16* __restrict__ BtB,
                                               const float* __restrict__ bias,
                                               void* __restrict__ CB,
                                               int M, int N, int K) {
    constexpr int BM = 128, BK = 64;
    const int tid = threadIdx.x, lane = tid & 63, wv = tid >> 6;
    const int l16 = lane & 15, kq = lane >> 4;
    const int row0 = blockIdx.x * BM, col0 = blockIdx.y * BN;
    const size_t czs = (size_t)M * N;
    const __hip_bfloat16* Bt = BtB + (size_t)blockIdx.z * N * K;

    __shared__ __align__(16) __hip_bfloat16 As[2][BM][BK];  // 16 KB x2, XOR-swizzled

    auto stageA = [&](int k0, int b) {
#pragma unroll
        for (int c = 0; c < 4; ++c) {
            int off = (tid + c * 256) * 16;
            int rr = off >> 7;             // LDS row (128B rows)
            int ch = (off >> 4) & 7;       // 16B chunk
            int chs = ch ^ (rr & 7);       // inverse-swizzled source chunk
            gld16((char*)&As[b][0][0] + off, A + (size_t)(row0 + rr) * K + k0 + chs * 8);
        }
    };

    float4v acc[2][BN / 16];
#pragma unroll
    for (int mf = 0; mf < 2; ++mf)
#pragma unroll
        for (int nf = 0; nf < BN / 16; ++nf) acc[mf][nf] = (float4v){0.f, 0.f, 0.f, 0.f};

    const int nk = K / BK;
    stageA(0, 0);
    for (int t = 0; t < nk; ++t) {
        int k0 = t * BK, cur = t & 1;
        if (t + 1 < nk) stageA(k0 + BK, cur ^ 1);
        short8v bfr[BN / 16][2];
#pragma unroll
        for (int nf = 0; nf < BN / 16; ++nf)
#pragma unroll
            for (int ks = 0; ks < 2; ++ks)
                bfr[nf][ks] = *(const short8v*)(Bt + (size_t)(col0 + nf * 16 + l16) * K +
                                                k0 + ks * 32 + kq * 8);
        __syncthreads();
        const char* asb = (const char*)&As[cur][0][0];
#pragma unroll
        for (int ks = 0; ks < 2; ++ks) {
            short8v afr[2];
#pragma unroll
            for (int mf = 0; mf < 2; ++mf) {
                int rr = wv * 32 + mf * 16 + l16;
                afr[mf] = *(const short8v*)(asb + rr * 128 +
                                            ((ks * 64 + kq * 16) ^ ((rr & 7) << 4)));
            }
#pragma unroll
            for (int mf = 0; mf < 2; ++mf)
#pragma unroll
                for (int nf = 0; nf < BN / 16; ++nf)
                    acc[mf][nf] = __builtin_amdgcn_mfma_f32_16x16x32_bf16(
                        afr[mf], bfr[nf][ks], acc[mf][nf], 0, 0, 0);
        }
        __syncthreads();
    }

#pragma unroll
    for (int mf = 0; mf < 2; ++mf)
#pragma unroll
        for (int nf = 0; nf < BN / 16; ++nf) {
            int rb = row0 + wv * 32 + mf * 16 + kq * 4;
            int col = col0 + nf * 16 + l16;
            if constexpr (OUTMODE == 0) {
                float bb = bias ? bias[col] : 0.f;
                float* C = (float*)CB + (size_t)blockIdx.z * czs;
#pragma unroll
                for (int e = 0; e < 4; ++e) C[(size_t)(rb + e) * N + col] = acc[mf][nf][e] + bb;
            } else {
                ushort4 u;
                u.x = (unsigned short)(pkbf(acc[mf][nf][0], 0.f) & 0xffff);
                u.y = (unsigned short)(pkbf(acc[mf][nf][1], 0.f) & 0xffff);
                u.z = (unsigned short)(pkbf(acc[mf][nf][2], 0.f) & 0xffff);
                u.w = (unsigned short)(pkbf(acc[mf][nf][3], 0.f) & 0xffff);
                unsigned short* Ct = (unsigned short*)CB + (size_t)blockIdx.z * czs;
                *(ushort4*)&Ct[(size_t)col * M + rb] = u;
            }
        }
}

// ---------------- f1/f2 + softmax factor tables from WhT (bf16, coalesced) ----------------
__global__ __launch_bounds__(256) void fvec_k(const __hip_bfloat16* __restrict__ WhT,
                                              const float* __restrict__ a,
                                              float* __restrict__ f1, float* __restrict__ f2,
                                              float2* __restrict__ pns,
                                              int M, int D, long long sWh, long long sa) {
    int zz = blockIdx.y;
    const __hip_bfloat16* W = WhT + (long long)zz * sWh;
    const float* az = a + (long long)zz * sa;
    int i = blockIdx.x * 256 + threadIdx.x;
    float s1 = 0.f, s2 = 0.f;
    for (int k = 0; k < D; k++) {
        float ww = __bfloat162float(W[(size_t)k * M + i]);
        s1 = fmaf(ww, az[k], s1);
        s2 = fmaf(ww, az[D + k], s2);
    }
    f1[(size_t)zz * M + i] = s1;
    f2[(size_t)zz * M + i] = s2;
    pns[(size_t)zz * M + i] = make_float2(exp2f(L2E * s2), exp2f(L2E * 0.2f * s2));
}

// ---------------- per-batch max of f2 ----------------
__global__ __launch_bounds__(256) void rmax_k(const float* __restrict__ f2,
                                              float* __restrict__ out, int M, long long s) {
    int zz = blockIdx.x;
    const float* p = f2 + (long long)zz * s;
    float m = -1e30f;
    for (int t = threadIdx.x; t < M; t += 256) m = fmaxf(m, p[t]);
    __shared__ float red[256];
    red[threadIdx.x] = m;
    __syncthreads();
    for (int off = 128; off > 0; off >>= 1) {
        if (threadIdx.x < off) red[threadIdx.x] = fmaxf(red[threadIdx.x], red[threadIdx.x + off]);
        __syncthreads();
    }
    if (threadIdx.x == 0) out[zz] = red[0];
}

// ---------------- MFMA masked-softmax attention aggregation (partials) ----------------
// P on VALU (w = max(Pp*e^{f2}, Nn*e^{0.2 f2}) — exact lrelu-exp identity), bf16 into
// double-buffered swizzled Ps (ONE barrier/tile); B-frags straight from L2 (WhT rows);
// pn factors via wave-uniform scalar loads. Always writes unnormalized f32 partial + Z
// into slot (chunk*HEADS + head); shared row-max (global f2 max) makes combine additive.
template <int FOUT, int HEADS>
__global__ __launch_bounds__(256) void attnm_k(const __hip_bfloat16* __restrict__ WhTB,
                                               const float* __restrict__ f1B,
                                               const float2* __restrict__ pnsB,
                                               const float* __restrict__ M2B,
                                               const unsigned int* __restrict__ mask32,
                                               float* __restrict__ partB,
                                               float* __restrict__ ZB,
                                               int jch) {
    constexpr int NN = 4096, TJ = 128;
    constexpr int MF = (FOUT == 64) ? 2 : 1;
    constexpr int NF = (FOUT == 64) ? 2 : 1;
    const int tid = threadIdx.x;
    const int lane = tid & 63;
    const int wv = tid >> 6;
    const int jg = __builtin_amdgcn_readfirstlane(wv);
    const int i0 = blockIdx.x * 64;
    const int l16 = lane & 15, kq = lane >> 4;
    const int r = lane;
    const int head = (HEADS > 1) ? blockIdx.y : 0;
    const int chunk = blockIdx.z;
    const int slot = chunk * HEADS + head;
    const int jlo = chunk * jch;
    const int nt = jch / TJ;

    const __hip_bfloat16* wt = WhTB + (size_t)head * FOUT * NN;
    const float* f1p = f1B + (size_t)head * NN;
    const float2* pnp = pnsB + (size_t)head * NN;
    const float M2 = M2B[(HEADS > 1) ? head : 0];

    __shared__ __align__(16) __hip_bfloat16 Ps[2][64][TJ];
    __shared__ float Zs[64][4];

    float f1i = f1p[i0 + r];
    float t0 = f1i + M2;
    float m = fmaxf(t0, 0.2f * t0);          // lrelu upper bound of row max (exact softmax)
    float Pp = exp2f(L2E * (f1i - m));
    float Nn = exp2f(L2E * (0.2f * f1i - m));
    float Z = 0.f;

    float4v acc[MF][NF];
#pragma unroll
    for (int mf = 0; mf < MF; ++mf)
#pragma unroll
        for (int nf = 0; nf < NF; ++nf) acc[mf][nf] = (float4v){0.f, 0.f, 0.f, 0.f};

    const int rowb = (FOUT == 64) ? (wv & 1) * 32 : wv * 16;
    const int colb = (FOUT == 64) ? (wv >> 1) * 32 : 0;
    const int swzP = (r & 7) << 4;
    const unsigned int* mrowp = mask32 + (size_t)(i0 + r) * (NN >> 5) + jg;
    char* psbase = (char*)&Ps[0][0][0];

    auto pcompute = [&](int jt, int buf, unsigned int mw) {
        const float2* pw = pnp + jt + jg * 32;   // wave-uniform -> s_load
        char* pd = psbase + buf * (64 * TJ * 2) + r * 256;
#pragma unroll
        for (int b = 0; b < 4; ++b) {
            float w[8];
#pragma unroll
            for (int e = 0; e < 8; ++e) {
                float2 pn = pw[b * 8 + e];
                float ww = fmaxf(Pp * pn.x, Nn * pn.y);
                ww = (mw & (1u << (b * 8 + e))) ? ww : 0.f;
                Z += ww;
                w[e] = ww;
            }
            uint4 pkv;
            pkv.x = pkbf(w[0], w[1]);
            pkv.y = pkbf(w[2], w[3]);
            pkv.z = pkbf(w[4], w[5]);
            pkv.w = pkbf(w[6], w[7]);
            *(uint4*)(pd + ((jg * 64 + b * 16) ^ swzP)) = pkv;
        }
    };

    pcompute(jlo, 0, mrowp[jlo >> 5]);

    for (int t = 0; t < nt; ++t) {
        int jt = jlo + t * TJ;
        __syncthreads();                         // Ps[t&1] ready for all waves
        short8v bfr[4][NF];                      // B-frags for tile t, straight from L2
#pragma unroll
        for (int kt = 0; kt < 4; ++kt)
#pragma unroll
            for (int nf = 0; nf < NF; ++nf)
                bfr[kt][nf] = *(const short8v*)(wt + (size_t)(colb + nf * 16 + l16) * NN +
                                                jt + kt * 32 + kq * 8);
        if (t + 1 < nt) pcompute(jt + TJ, (t + 1) & 1, mrowp[(jt + TJ) >> 5]);
        const char* psb = psbase + (t & 1) * (64 * TJ * 2);
#pragma unroll
        for (int kt = 0; kt < 4; ++kt) {
            short8v afr[MF];
#pragma unroll
            for (int mf = 0; mf < MF; ++mf) {
                int row = rowb + mf * 16 + l16;
                afr[mf] = *(const short8v*)(psb + row * 256 +
                                            ((kt * 64 + kq * 16) ^ ((row & 7) << 4)));
            }
#pragma unroll
            for (int mf = 0; mf < MF; ++mf)
#pragma unroll
                for (int nf = 0; nf < NF; ++nf)
                    acc[mf][nf] = __builtin_amdgcn_mfma_f32_16x16x32_bf16(
                        afr[mf], bfr[kt][nf], acc[mf][nf], 0, 0, 0);
        }
    }

    Zs[r][wv] = Z;
    __syncthreads();
    if (tid < 64) {
        float zs = Zs[tid][0] + Zs[tid][1] + Zs[tid][2] + Zs[tid][3];
        ZB[(size_t)slot * NN + i0 + tid] = zs;
    }

#pragma unroll
    for (int mf = 0; mf < MF; ++mf)
#pragma unroll
        for (int nf = 0; nf < NF; ++nf) {
            int rb = rowb + mf * 16 + kq * 4;
            int col = colb + nf * 16 + l16;
#pragma unroll
            for (int e = 0; e < 4; ++e)
                partB[((size_t)slot * NN + i0 + rb + e) * FOUT + col] = acc[mf][nf][e];
        }
}

// ---------------- combine head-pass partials (2 chunks x 8 heads) -> bf16 hc ----------------
__global__ __launch_bounds__(256) void combH_k(const float* __restrict__ part,
                                               const float* __restrict__ Zp,
                                               unsigned short* __restrict__ hcb, int N) {
    int id = blockIdx.x * 256 + threadIdx.x;       // N*512
    int i = id >> 9, hf = id & 511;
    int h = hf >> 6, f = hf & 63;
    float s = part[((size_t)h * N + i) * 64 + f] + part[((size_t)(8 + h) * N + i) * 64 + f];
    float Z = Zp[(size_t)h * N + i] + Zp[(size_t)(8 + h) * N + i];
    float o = s / Z;
    o = (o > 0.f) ? o : (__expf(o) - 1.f);         // elu
    hcb[id] = (unsigned short)(pkbf(o, 0.f) & 0xffff);
}

// ---------------- combine j-split partials ----------------
__global__ __launch_bounds__(256) void comb2_k(const float* __restrict__ part,
                                               const float* __restrict__ Zp,
                                               const float* __restrict__ orig,
                                               float* __restrict__ zout,
                                               unsigned short* __restrict__ zb, int N) {
    int id = blockIdx.x * 256 + threadIdx.x;  // N*64
    int i = id >> 6, f = id & 63;
    float Zs = 0.f, s = 0.f;
#pragma unroll
    for (int c = 0; c < 8; c++) Zs += Zp[(size_t)c * N + i];
#pragma unroll
    for (int c = 0; c < 8; c++) s += part[((size_t)c * N + i) * 64 + f];
    float v = s / Zs + orig[id];
    zout[id] = v;
    zb[id] = (unsigned short)(pkbf(v, 0.f) & 0xffff);
}

__global__ __launch_bounds__(256) void comb1_k(const float* __restrict__ part,
                                               const float* __restrict__ Zp,
                                               float* __restrict__ cls, int N) {
    int id = blockIdx.x * 256 + threadIdx.x;  // N*16
    int i = id >> 4, f = id & 15;
    float Zs = 0.f, s = 0.f;
#pragma unroll
    for (int c = 0; c < 8; c++) Zs += Zp[(size_t)c * N + i];
#pragma unroll
    for (int c = 0; c < 8; c++) s += part[((size_t)c * N + i) * 16 + f];
    float o = s / Zs;
    cls[id] = (o > 0.f) ? o : (expf(o) - 1.f);
}

// ---------------- fused: log_softmax(cls) -> out1 ; z @ w_deg + b -> out2 ----------------
__global__ __launch_bounds__(256) void fin_k(const float* __restrict__ cls,
                                             const float* __restrict__ zbuf,
                                             const float* __restrict__ wd,
                                             const float* __restrict__ bd,
                                             float* __restrict__ out, int N) {
    int i = blockIdx.x * 256 + threadIdx.x;
    if (i >= N) return;
    float v[16];
    float m = -1e30f;
#pragma unroll
    for (int k = 0; k < 16; k++) {
        v[k] = cls[(size_t)i * 16 + k];
        m = fmaxf(m, v[k]);
    }
    float s = 0.f;
#pragma unroll
    for (int k = 0; k < 16; k++) s += expf(v[k] - m);
    float l = m + logf(s);
#pragma unroll
    for (int k = 0; k < 16; k++) out[(size_t)i * 16 + k] = v[k] - l;
    float s2 = bd[0];
#pragma unroll
    for (int k = 0; k < 64; k++) s2 = fmaf(zbuf[(size_t)i * 64 + k], wd[k], s2);
    out[(size_t)N * 16 + i] = s2;
}

extern "C" void kernel_launch(void* const* d_in, const int* in_sizes, int n_in,
                              void* d_out, int out_size, void* d_ws, size_t ws_size,
                              hipStream_t stream) {
    const float* x = (const float*)d_in[0];
    const int* adj = (const int*)d_in[1];
    const float* W_att = (const float*)d_in[2];
    const float* a_att = (const float*)d_in[3];
    const float* W_out1 = (const float*)d_in[4];
    const float* a_out1 = (const float*)d_in[5];
    const float* W_out2 = (const float*)d_in[6];
    const float* a_out2 = (const float*)d_in[7];
    const float* W_down = (const float*)d_in[8];
    const float* b_down = (const float*)d_in[9];
    const float* w_deg = (const float*)d_in[10];
    const float* b_deg = (const float*)d_in[11];
    const float* W_deg3 = (const float*)d_in[12];
    const float* b_deg3 = (const float*)d_in[13];
    float* out = (float*)d_out;

    constexpr int N = 4096, NF = 512, NH = 64, NC = 16, H = 8, DM = 128;

    char* wp = (char*)d_ws;
    auto alloc = [&](size_t b) {
        char* p = wp;
        wp += (b + 255) & ~(size_t)255;
        return p;
    };
    unsigned long long* mask = (unsigned long long*)alloc((size_t)N * N / 8);
    unsigned short* xb = (unsigned short*)alloc((size_t)N * NF * 2);
    unsigned short* WT10 = (unsigned short*)alloc((size_t)10 * NH * NF * 2);
    unsigned short* Wo1T = (unsigned short*)alloc((size_t)NC * NF * 2);
    unsigned short* Wd3T = (unsigned short*)alloc((size_t)DM * NH * 2);
    unsigned short* WhT = (unsigned short*)alloc((size_t)H * NH * N * 2);
    float* f1h = (float*)alloc((size_t)H * N * 4);
    float* f2h = (float*)alloc((size_t)H * N * 4);
    float2* pns_h = (float2*)alloc((size_t)H * N * 8);
    float* M2 = (float*)alloc(256);
    float* parth = (float*)alloc((size_t)16 * N * NH * 4);
    float* Zh = (float*)alloc((size_t)16 * N * 4);
    unsigned short* hcb = (unsigned short*)alloc((size_t)N * NF * 2);
    float* orig = (float*)alloc((size_t)N * NH * 4);
    unsigned short* Wh1T = (unsigned short*)alloc((size_t)NC * N * 2);
    unsigned short* Wh2T = (unsigned short*)alloc((size_t)NH * N * 2);
    float* f1o1 = (float*)alloc((size_t)N * 4);
    float* f2o1 = (float*)alloc((size_t)N * 4);
    float* f1o2 = (float*)alloc((size_t)N * 4);
    float* f2o2 = (float*)alloc((size_t)N * 4);
    float2* pns_o1 = (float2*)alloc((size_t)N * 8);
    float2* pns_o2 = (float2*)alloc((size_t)N * 8);
    float* part1 = (float*)alloc((size_t)8 * N * NC * 4);
    float* Z1 = (float*)alloc((size_t)8 * N * 4);
    float* part2 = (float*)alloc((size_t)8 * N * NH * 4);
    float* Z2 = (float*)alloc((size_t)8 * N * 4);
    float* zbuf = (float*)alloc((size_t)N * NH * 4);
    unsigned short* zb = (unsigned short*)alloc((size_t)N * NH * 2);
    float* cls = (float*)alloc((size_t)N * NC * 4);

    const unsigned int* mask32 = (const unsigned int*)mask;

    // 1. pack adjacency bitmask; x -> bf16; weights -> [N][K] bf16 (one batched tpose)
    pack_k<<<(size_t)N * N / 256, 256, 0, stream>>>(adj, mask);
    cvt_k<<<(N * NF / 8 + 255) / 256, 256, 0, stream>>>(x, xb, N * NF / 8);
    tposeSel_k<<<dim3(NF / 64, NH / 16, 10), 256, 0, stream>>>(W_att, W_down, W_out2, WT10,
                                                               NF, NH);
    tpose_k<<<dim3(NF / 64, NC / 16, 1), 256, 0, stream>>>(W_out1, Wo1T, NF, NC);
    tpose_k<<<dim3(1, DM / 16, 1), 256, 0, stream>>>(W_deg3, Wd3T, NH, DM);
    // 2. WhT[h] = (xb @ W_att[h])^T bf16; orig = x@W_down + b (f32)
    gemmb_k<64, 1><<<dim3(N / 128, 1, H), 256, 0, stream>>>(
        (const __hip_bfloat16*)xb, (const __hip_bfloat16*)WT10, nullptr, WhT, N, NH, NF);
    gemmb_k<64, 0><<<dim3(N / 128, 1, 1), 256, 0, stream>>>(
        (const __hip_bfloat16*)xb, (const __hip_bfloat16*)(WT10 + (size_t)8 * NH * NF),
        b_down, orig, N, NH, NF);
    // 3. f1/f2/pns per head + per-head max(f2)
    fvec_k<<<dim3(N / 256, H), 256, 0, stream>>>((const __hip_bfloat16*)WhT, a_att, f1h, f2h,
                                                 pns_h, N, NH, (long long)NH * N, 2 * NH);
    rmax_k<<<H, 256, 0, stream>>>(f2h, M2, N, N);
    // 4. 8-head MFMA attention, 2-way j-split (1024 blocks, 4/CU) -> partials, then combine
    attnm_k<64, 8><<<dim3(N / 64, H, 2), 256, 0, stream>>>(
        (const __hip_bfloat16*)WhT, f1h, pns_h, M2, mask32, parth, Zh, N / 2);
    combH_k<<<(size_t)N * 512 / 256, 256, 0, stream>>>(parth, Zh, hcb, N);
    // 5. second-layer projections (transposed bf16 outputs) + f-vectors
    gemmb_k<64, 1><<<dim3(N / 128, 1, 1), 256, 0, stream>>>(
        (const __hip_bfloat16*)hcb, (const __hip_bfloat16*)(WT10 + (size_t)9 * NH * NF),
        nullptr, Wh2T, N, NH, NF);
    gemmb_k<16, 1><<<dim3(N / 128, 1, 1), 256, 0, stream>>>(
        (const __hip_bfloat16*)hcb, (const __hip_bfloat16*)Wo1T, nullptr, Wh1T, N, NC, NF);
    fvec_k<<<dim3(N / 256, 1), 256, 0, stream>>>((const __hip_bfloat16*)Wh2T, a_out2, f1o2, f2o2,
                                                 pns_o2, N, NH, 0, 0);
    fvec_k<<<dim3(N / 256, 1), 256, 0, stream>>>((const __hip_bfloat16*)Wh1T, a_out1, f1o1, f2o1,
                                                 pns_o1, N, NC, 0, 0);
    rmax_k<<<1, 256, 0, stream>>>(f2o1, M2 + 8, N, 0);
    rmax_k<<<1, 256, 0, stream>>>(f2o2, M2 + 9, N, 0);
    // 6. out2/out1 MFMA attention, 8-way j-split (shared row-max -> additive combine)
    attnm_k<64, 1><<<dim3(N / 64, 1, 8), 256, 0, stream>>>(
        (const __hip_bfloat16*)Wh2T, f1o2, pns_o2, M2 + 9, mask32, part2, Z2, N / 8);
    attnm_k<16, 1><<<dim3(N / 64, 1, 8), 256, 0, stream>>>(
        (const __hip_bfloat16*)Wh1T, f1o1, pns_o1, M2 + 8, mask32, part1, Z1, N / 8);
    comb2_k<<<(size_t)N * 64 / 256, 256, 0, stream>>>(part2, Z2, orig, zbuf, zb, N);
    comb1_k<<<(size_t)N * 16 / 256, 256, 0, stream>>>(part1, Z1, cls, N);
    // 7. outputs
    fin_k<<<N / 256, 256, 0, stream>>>(cls, zbuf, w_deg, b_deg, out, N);
    gemmb_k<64, 0><<<dim3(N / 128, DM / 64, 1), 256, 0, stream>>>(
        (const __hip_bfloat16*)zb, (const __hip_bfloat16*)Wd3T, b_deg3,
        out + (size_t)N * NC + N, N, DM, NH);
}

// Round 6
// 311.626 us; speedup vs baseline: 4.9395x; 1.1956x over previous
//
#include <hip/hip_runtime.h>
#include <hip/hip_bf16.h>

#define L2E 1.44269504088896f

typedef __attribute__((ext_vector_type(8))) short short8v;
typedef __attribute__((ext_vector_type(8))) _Float16 half8v;
typedef __attribute__((ext_vector_type(4))) float float4v;

__device__ __forceinline__ void gld16(void* lds, const void* gp) {
    __builtin_amdgcn_global_load_lds(
        (const __attribute__((address_space(1))) unsigned int*)gp,
        (__attribute__((address_space(3))) unsigned int*)lds, 16, 0, 0);
}
__device__ __forceinline__ unsigned pkbf(float a, float b) {
    unsigned r;
    asm("v_cvt_pk_bf16_f32 %0, %1, %2" : "=v"(r) : "v"(a), "v"(b));
    return r;
}
__device__ __forceinline__ unsigned pkrtz(float a, float b) {
    unsigned r;
    asm("v_cvt_pkrtz_f16_f32 %0, %1, %2" : "=v"(r) : "v"(a), "v"(b));
    return r;
}
__device__ __forceinline__ unsigned pkmul(unsigned a, unsigned b) {
    unsigned r;
    asm("v_pk_mul_f16 %0, %1, %2" : "=v"(r) : "v"(a), "v"(b));
    return r;
}
__device__ __forceinline__ unsigned pkmax(unsigned a, unsigned b) {
    unsigned r;
    asm("v_pk_max_f16 %0, %1, %2" : "=v"(r) : "v"(a), "v"(b));
    return r;
}

// ---------------- prep: pack adj, cvt x->bf16, all weight transposes ----------------
__device__ __forceinline__ void tp_body(const float* __restrict__ src,
                                        unsigned short* __restrict__ dst,
                                        int M, int F, int j0, int f0, float (*t)[17]) {
    int tid = threadIdx.x;
    int rr = tid >> 2, c0 = (tid & 3) * 4;
    float4 v = *(const float4*)&src[(size_t)(j0 + rr) * F + f0 + c0];
    t[rr][c0 + 0] = v.x;
    t[rr][c0 + 1] = v.y;
    t[rr][c0 + 2] = v.z;
    t[rr][c0 + 3] = v.w;
    __syncthreads();
    int f = tid >> 4, jl = (tid & 15) * 4;
    ushort4 o;
    o.x = (unsigned short)(pkbf(t[jl + 0][f], 0.f) & 0xffff);
    o.y = (unsigned short)(pkbf(t[jl + 1][f], 0.f) & 0xffff);
    o.z = (unsigned short)(pkbf(t[jl + 2][f], 0.f) & 0xffff);
    o.w = (unsigned short)(pkbf(t[jl + 3][f], 0.f) & 0xffff);
    *(ushort4*)&dst[(size_t)(f0 + f) * M + j0 + jl] = o;
}

__global__ __launch_bounds__(256) void prep_k(const int* __restrict__ adj,
                                              unsigned long long* __restrict__ mask,
                                              const float* __restrict__ x,
                                              unsigned short* __restrict__ xb,
                                              const float* __restrict__ W_att,
                                              const float* __restrict__ W_down,
                                              const float* __restrict__ W_out2,
                                              const float* __restrict__ W_out1,
                                              const float* __restrict__ W_deg3,
                                              unsigned short* __restrict__ WT,
                                              unsigned short* __restrict__ Wd3T) {
    __shared__ float tbuf[64][17];
    int bx = blockIdx.x, tid = threadIdx.x;
    if (bx < 65536) {                                   // pack adj bitmask
        size_t idx = (size_t)bx * 256 + tid;
        unsigned long long b = __ballot(adj[idx] > 0);
        if ((tid & 63) == 0) mask[idx >> 6] = b;
    } else if (bx < 66560) {                            // x -> bf16
        int i = (bx - 65536) * 256 + tid;
        float4 a = ((const float4*)x)[i * 2];
        float4 b = ((const float4*)x)[i * 2 + 1];
        uint4 o = {pkbf(a.x, a.y), pkbf(a.z, a.w), pkbf(b.x, b.y), pkbf(b.z, b.w)};
        ((uint4*)xb)[i] = o;
    } else if (bx < 66880) {                            // W_att/W_down/W_out2 -> WT[0..9]
        int r = bx - 66560;
        int z = r >> 5, rr = r & 31;
        const float* src = (z < 8) ? W_att + (size_t)z * 512 * 64 : ((z == 8) ? W_down : W_out2);
        tp_body(src, WT + (size_t)z * 64 * 512, 512, 64, (rr & 7) * 64, (rr >> 3) * 16, tbuf);
    } else if (bx < 66888) {                            // W_out1 -> WT rows 640..655
        int r = bx - 66880;
        tp_body(W_out1, WT + (size_t)640 * 512, 512, 16, r * 64, 0, tbuf);
    } else {                                            // W_deg3 [64][128] -> Wd3T [128][64]
        int r = bx - 66888;
        tp_body(W_deg3, Wd3T, 64, 128, 0, r * 16, tbuf);
    }
}

// ---------------- bf16 MFMA GEMM: C = A[MxK] @ Bt[NxK]^T ----------------
// OUTMODE 0: C f32 [Z][M][N] (+bias);  OUTMODE 1: C fp16 [Z][N][M] (transposed)
template <int BN, int OUTMODE>
__global__ __launch_bounds__(256) void gemmb_k(const __hip_bfloat16* __restrict__ A,
                                               const __hip_bfloat16* __restrict__ BtB,
                                               const float* __restrict__ bias,
                                               void* __restrict__ CB,
                                               int M, int N, int K) {
    constexpr int BM = 128, BK = 64;
    const int tid = threadIdx.x, lane = tid & 63, wv = tid >> 6;
    const int l16 = lane & 15, kq = lane >> 4;
    const int row0 = blockIdx.x * BM, col0 = blockIdx.y * BN;
    const size_t czs = (size_t)M * N;
    const __hip_bfloat16* Bt = BtB + (size_t)blockIdx.z * N * K;

    __shared__ __align__(16) __hip_bfloat16 As[2][BM][BK];

    auto stageA = [&](int k0, int b) {
#pragma unroll
        for (int c = 0; c < 4; ++c) {
            int off = (tid + c * 256) * 16;
            int rr = off >> 7;
            int ch = (off >> 4) & 7;
            int chs = ch ^ (rr & 7);
            gld16((char*)&As[b][0][0] + off, A + (size_t)(row0 + rr) * K + k0 + chs * 8);
        }
    };

    float4v acc[2][BN / 16];
#pragma unroll
    for (int mf = 0; mf < 2; ++mf)
#pragma unroll
        for (int nf = 0; nf < BN / 16; ++nf) acc[mf][nf] = (float4v){0.f, 0.f, 0.f, 0.f};

    const int nk = K / BK;
    stageA(0, 0);
    for (int t = 0; t < nk; ++t) {
        int k0 = t * BK, cur = t & 1;
        if (t + 1 < nk) stageA(k0 + BK, cur ^ 1);
        short8v bfr[BN / 16][2];
#pragma unroll
        for (int nf = 0; nf < BN / 16; ++nf)
#pragma unroll
            for (int ks = 0; ks < 2; ++ks)
                bfr[nf][ks] = *(const short8v*)(Bt + (size_t)(col0 + nf * 16 + l16) * K +
                                                k0 + ks * 32 + kq * 8);
        __syncthreads();
        const char* asb = (const char*)&As[cur][0][0];
#pragma unroll
        for (int ks = 0; ks < 2; ++ks) {
            short8v afr[2];
#pragma unroll
            for (int mf = 0; mf < 2; ++mf) {
                int rr = wv * 32 + mf * 16 + l16;
                afr[mf] = *(const short8v*)(asb + rr * 128 +
                                            ((ks * 64 + kq * 16) ^ ((rr & 7) << 4)));
            }
#pragma unroll
            for (int mf = 0; mf < 2; ++mf)
#pragma unroll
                for (int nf = 0; nf < BN / 16; ++nf)
                    acc[mf][nf] = __builtin_amdgcn_mfma_f32_16x16x32_bf16(
                        afr[mf], bfr[nf][ks], acc[mf][nf], 0, 0, 0);
        }
        __syncthreads();
    }

#pragma unroll
    for (int mf = 0; mf < 2; ++mf)
#pragma unroll
        for (int nf = 0; nf < BN / 16; ++nf) {
            int rb = row0 + wv * 32 + mf * 16 + kq * 4;
            int col = col0 + nf * 16 + l16;
            if constexpr (OUTMODE == 0) {
                float bb = bias ? bias[col] : 0.f;
                float* C = (float*)CB + (size_t)blockIdx.z * czs;
#pragma unroll
                for (int e = 0; e < 4; ++e) C[(size_t)(rb + e) * N + col] = acc[mf][nf][e] + bb;
            } else {
                uint2 u = {pkrtz(acc[mf][nf][0], acc[mf][nf][1]),
                           pkrtz(acc[mf][nf][2], acc[mf][nf][3])};
                unsigned short* Ct = (unsigned short*)CB + (size_t)blockIdx.z * czs;
                *(uint2*)&Ct[(size_t)col * M + rb] = u;
            }
        }
}

// ---------------- f1/f2 from fp16 WhT (coalesced) ----------------
__global__ __launch_bounds__(256) void fvh_k(const _Float16* __restrict__ WhT,
                                             const float* __restrict__ a,
                                             float* __restrict__ f1, float* __restrict__ f2) {
    int zz = blockIdx.y;
    const _Float16* W = WhT + (size_t)zz * 64 * 4096;
    const float* az = a + (size_t)zz * 128;
    int i = blockIdx.x * 256 + threadIdx.x;
    float s1 = 0.f, s2 = 0.f;
    for (int k = 0; k < 64; k++) {
        float ww = (float)W[(size_t)k * 4096 + i];
        s1 = fmaf(ww, az[k], s1);
        s2 = fmaf(ww, az[64 + k], s2);
    }
    f1[(size_t)zz * 4096 + i] = s1;
    f2[(size_t)zz * 4096 + i] = s2;
}

__global__ __launch_bounds__(256) void fvo_k(const _Float16* __restrict__ Wh12T,
                                             const float* __restrict__ a2,
                                             const float* __restrict__ a1,
                                             float* __restrict__ f1o, float* __restrict__ f2o) {
    int y = blockIdx.y;
    const _Float16* W = Wh12T + (y ? (size_t)64 * 4096 : 0);
    const float* a = y ? a1 : a2;
    int D = y ? 16 : 64;
    int i = blockIdx.x * 256 + threadIdx.x;
    float s1 = 0.f, s2 = 0.f;
    for (int k = 0; k < D; k++) {
        float ww = (float)W[(size_t)k * 4096 + i];
        s1 = fmaf(ww, a[k], s1);
        s2 = fmaf(ww, a[D + k], s2);
    }
    f1o[(size_t)y * 4096 + i] = s1;
    f2o[(size_t)y * 4096 + i] = s2;
}

// ---------------- per-batch max of f2 + fp16 pn pair-table ----------------
__global__ __launch_bounds__(256) void rmaxpn_k(const float* __restrict__ f2B,
                                                float* __restrict__ M2out,
                                                uint2* __restrict__ pnB) {
    int z = blockIdx.x, tid = threadIdx.x;
    const float* f2 = f2B + (size_t)z * 4096;
    uint2* pn = pnB + (size_t)z * 2048;
    __shared__ float red[256];
    float m = -1e30f;
    for (int t = tid; t < 4096; t += 256) m = fmaxf(m, f2[t]);
    red[tid] = m;
    __syncthreads();
    for (int off = 128; off > 0; off >>= 1) {
        if (tid < off) red[tid] = fmaxf(red[tid], red[tid + off]);
        __syncthreads();
    }
    float M2 = red[0];
    if (tid == 0) M2out[z] = M2;
    for (int p = tid; p < 2048; p += 256) {
        float a0 = f2[2 * p] - M2, a1 = f2[2 * p + 1] - M2;
        uint2 q;
        q.x = pkrtz(exp2f(L2E * a0), exp2f(L2E * a1));
        q.y = pkrtz(exp2f(0.2f * L2E * a0), exp2f(0.2f * L2E * a1));
        pn[p] = q;
    }
}

// ---------------- fp16 MFMA masked-softmax attention (partials + Z-via-MFMA) ----------------
// w = max(Pp'*pn.x, Nn'*pn.y) with Pp'=e^{min(0,.8t0)}, Nn'=e^{-max(0,.8t0)} (exact lrelu-exp
// identity, both factors <=1 -> fp16-safe). Packed v_pk ops, LUT mask, Z via ones-column MFMA.
template <int FOUT>
__device__ __forceinline__ void attn_body(const _Float16* __restrict__ wt,
                                          const float* __restrict__ f1p,
                                          const uint2* __restrict__ pnp, float M2,
                                          const unsigned* __restrict__ mask32,
                                          float* __restrict__ part, float* __restrict__ Zb,
                                          int i0, int jlo, int nt,
                                          char* psbase, unsigned long long* lut) {
    constexpr int NN = 4096, TJ = 128;
    constexpr int MF = (FOUT == 64) ? 2 : 1;
    constexpr int NF = (FOUT == 64) ? 2 : 1;
    const int tid = threadIdx.x, lane = tid & 63, wv = tid >> 6;
    const int jg = __builtin_amdgcn_readfirstlane(wv);
    const int l16 = lane & 15, kq = lane >> 4, r = lane;

    if (tid < 16) {
        unsigned lo = ((tid & 1) ? 0xFFFFu : 0u) | ((tid & 2) ? 0xFFFF0000u : 0u);
        unsigned hi = ((tid & 4) ? 0xFFFFu : 0u) | ((tid & 8) ? 0xFFFF0000u : 0u);
        lut[tid] = (unsigned long long)lo | ((unsigned long long)hi << 32);
    }

    float f1i = f1p[i0 + r];
    float t8 = 0.8f * (f1i + M2);
    unsigned Pp2, Nn2;
    {
        float Ppf = exp2f(L2E * fminf(0.f, t8));
        float Nnf = exp2f(-L2E * fmaxf(0.f, t8));
        Pp2 = pkrtz(Ppf, Ppf);
        Nn2 = pkrtz(Nnf, Nnf);
    }
    half8v ones;
#pragma unroll
    for (int k = 0; k < 8; ++k) ones[k] = (_Float16)1.0f;

    float4v acc[MF][NF], accz[MF];
#pragma unroll
    for (int mf = 0; mf < MF; ++mf) {
        accz[mf] = (float4v){0.f, 0.f, 0.f, 0.f};
#pragma unroll
        for (int nf = 0; nf < NF; ++nf) acc[mf][nf] = (float4v){0.f, 0.f, 0.f, 0.f};
    }

    const int rowb = (FOUT == 64) ? (wv & 1) * 32 : wv * 16;
    const int colb = (FOUT == 64) ? (wv >> 1) * 32 : 0;
    const int swz = (r & 7) << 4;
    const unsigned* mrowp = mask32 + (size_t)(i0 + r) * (NN >> 5) + (jlo >> 5) + jg;
    char* pd = psbase + r * 256;
    __syncthreads();  // lut visible

    for (int t = 0; t < nt; ++t) {
        int jt = jlo + t * TJ;
        unsigned mw = mrowp[t * 4];
        const uint2* pw = pnp + (jt >> 1) + jg * 16;
#pragma unroll
        for (int b = 0; b < 4; ++b) {
            unsigned long long m0 = lut[(mw >> (b * 8)) & 15];
            unsigned long long m1 = lut[(mw >> (b * 8 + 4)) & 15];
            uint2 q0 = pw[b * 4 + 0], q1 = pw[b * 4 + 1];
            uint2 q2 = pw[b * 4 + 2], q3 = pw[b * 4 + 3];
            uint4 w4;
            w4.x = pkmax(pkmul(Pp2, q0.x), pkmul(Nn2, q0.y)) & (unsigned)m0;
            w4.y = pkmax(pkmul(Pp2, q1.x), pkmul(Nn2, q1.y)) & (unsigned)(m0 >> 32);
            w4.z = pkmax(pkmul(Pp2, q2.x), pkmul(Nn2, q2.y)) & (unsigned)m1;
            w4.w = pkmax(pkmul(Pp2, q3.x), pkmul(Nn2, q3.y)) & (unsigned)(m1 >> 32);
            *(uint4*)(pd + ((jg * 64 + b * 16) ^ swz)) = w4;
        }
        __syncthreads();  // Ps ready
        half8v bfr[4][NF];
#pragma unroll
        for (int kt = 0; kt < 4; ++kt)
#pragma unroll
            for (int nf = 0; nf < NF; ++nf)
                bfr[kt][nf] = *(const half8v*)(wt + (size_t)(colb + nf * 16 + l16) * NN +
                                               jt + kt * 32 + kq * 8);
#pragma unroll
        for (int kt = 0; kt < 4; ++kt) {
            half8v afr[MF];
#pragma unroll
            for (int mf = 0; mf < MF; ++mf) {
                int row = rowb + mf * 16 + l16;
                afr[mf] = *(const half8v*)(psbase + row * 256 +
                                           ((kt * 64 + kq * 16) ^ ((row & 7) << 4)));
            }
#pragma unroll
            for (int mf = 0; mf < MF; ++mf) {
                accz[mf] = __builtin_amdgcn_mfma_f32_16x16x32_f16(afr[mf], ones, accz[mf],
                                                                  0, 0, 0);
#pragma unroll
                for (int nf = 0; nf < NF; ++nf)
                    acc[mf][nf] = __builtin_amdgcn_mfma_f32_16x16x32_f16(
                        afr[mf], bfr[kt][nf], acc[mf][nf], 0, 0, 0);
            }
        }
        __syncthreads();  // MFMA done before Ps overwrite
    }

#pragma unroll
    for (int mf = 0; mf < MF; ++mf)
#pragma unroll
        for (int nf = 0; nf < NF; ++nf) {
            int rbl = rowb + mf * 16 + kq * 4;
            int col = colb + nf * 16 + l16;
#pragma unroll
            for (int e = 0; e < 4; ++e)
                part[(size_t)(i0 + rbl + e) * FOUT + col] = acc[mf][nf][e];
        }
    if (colb == 0 && l16 == 0) {
#pragma unroll
        for (int mf = 0; mf < MF; ++mf)
#pragma unroll
            for (int e = 0; e < 4; ++e)
                Zb[i0 + rowb + mf * 16 + kq * 4 + e] = accz[mf][e];
    }
}

__global__ __launch_bounds__(256) void attnh_k(const _Float16* __restrict__ WhT,
                                               const float* __restrict__ f1h,
                                               const uint2* __restrict__ pnh,
                                               const float* __restrict__ M2,
                                               const unsigned* __restrict__ mask32,
                                               float* __restrict__ parth,
                                               float* __restrict__ Zh) {
    __shared__ __align__(16) char Ps[64 * 128 * 2];
    __shared__ unsigned long long lut[16];
    int head = blockIdx.y, chunk = blockIdx.z, slot = chunk * 8 + head;
    attn_body<64>(WhT + (size_t)head * 64 * 4096, f1h + (size_t)head * 4096,
                  pnh + (size_t)head * 2048, M2[head], mask32,
                  parth + (size_t)slot * 4096 * 64, Zh + (size_t)slot * 4096,
                  blockIdx.x * 64, chunk * 2048, 16, Ps, lut);
}

__global__ __launch_bounds__(256) void attno_k(const _Float16* __restrict__ Wh12T,
                                               const float* __restrict__ f1o,
                                               const uint2* __restrict__ pno,
                                               const float* __restrict__ M2,
                                               const unsigned* __restrict__ mask32,
                                               float* __restrict__ part2,
                                               float* __restrict__ Z2,
                                               float* __restrict__ part1,
                                               float* __restrict__ Z1) {
    __shared__ __align__(16) char Ps[64 * 128 * 2];
    __shared__ unsigned long long lut[16];
    int chunk = blockIdx.z;
    if (blockIdx.y == 0)
        attn_body<64>(Wh12T, f1o, pno, M2[8], mask32, part2 + (size_t)chunk * 4096 * 64,
                      Z2 + (size_t)chunk * 4096, blockIdx.x * 64, chunk * 512, 4, Ps, lut);
    else
        attn_body<16>(Wh12T + (size_t)64 * 4096, f1o + 4096, pno + 2048, M2[9], mask32,
                      part1 + (size_t)chunk * 4096 * 16, Z1 + (size_t)chunk * 4096,
                      blockIdx.x * 64, chunk * 512, 4, Ps, lut);
}

// ---------------- combine head-pass partials -> bf16 hc (elu) ----------------
__global__ __launch_bounds__(256) void combH_k(const float* __restrict__ part,
                                               const float* __restrict__ Zp,
                                               unsigned short* __restrict__ hcb, int N) {
    int id = blockIdx.x * 256 + threadIdx.x;  // N*512
    int i = id >> 9, hf = id & 511;
    int h = hf >> 6, f = hf & 63;
    float s = part[((size_t)h * N + i) * 64 + f] + part[((size_t)(8 + h) * N + i) * 64 + f];
    float Z = Zp[(size_t)h * N + i] + Zp[(size_t)(8 + h) * N + i];
    float o = s / Z;
    o = (o > 0.f) ? o : (__expf(o) - 1.f);
    hcb[id] = (unsigned short)(pkbf(o, 0.f) & 0xffff);
}

// ---------------- combine out2 partials + residual (origT fp16) -> zbuf f32 + zb bf16 ----
__global__ __launch_bounds__(256) void comb2_k(const float* __restrict__ part,
                                               const float* __restrict__ Zp,
                                               const _Float16* __restrict__ origT,
                                               const float* __restrict__ bdown,
                                               float* __restrict__ zout,
                                               unsigned short* __restrict__ zb, int N) {
    int id = blockIdx.x * 256 + threadIdx.x;  // N*64
    int i = id >> 6, f = id & 63;
    float Zs = 0.f, s = 0.f;
#pragma unroll
    for (int c = 0; c < 8; c++) Zs += Zp[(size_t)c * N + i];
#pragma unroll
    for (int c = 0; c < 8; c++) s += part[((size_t)c * N + i) * 64 + f];
    float v = s / Zs + (float)origT[(size_t)f * N + i] + bdown[f];
    zout[id] = v;
    zb[id] = (unsigned short)(pkbf(v, 0.f) & 0xffff);
}

// ---------------- comb1 + log_softmax + result2 ----------------
__global__ __launch_bounds__(256) void c1fin_k(const float* __restrict__ part1,
                                               const float* __restrict__ Z1,
                                               const float* __restrict__ zbuf,
                                               const float* __restrict__ wd,
                                               const float* __restrict__ bd,
                                               float* __restrict__ out, int N) {
    int i = blockIdx.x * 256 + threadIdx.x;
    float Z = 0.f;
#pragma unroll
    for (int c = 0; c < 8; c++) Z += Z1[(size_t)c * N + i];
    float v[16];
    float m = -1e30f;
#pragma unroll
    for (int f = 0; f < 16; f++) {
        float s = 0.f;
#pragma unroll
        for (int c = 0; c < 8; c++) s += part1[((size_t)c * N + i) * 16 + f];
        float o = s / Z;
        o = (o > 0.f) ? o : (expf(o) - 1.f);
        v[f] = o;
        m = fmaxf(m, o);
    }
    float se = 0.f;
#pragma unroll
    for (int f = 0; f < 16; f++) se += expf(v[f] - m);
    float l = m + logf(se);
#pragma unroll
    for (int f = 0; f < 16; f++) out[(size_t)i * 16 + f] = v[f] - l;
    float s2 = bd[0];
#pragma unroll
    for (int k = 0; k < 64; k++) s2 = fmaf(zbuf[(size_t)i * 64 + k], wd[k], s2);
    out[(size_t)N * 16 + i] = s2;
}

extern "C" void kernel_launch(void* const* d_in, const int* in_sizes, int n_in,
                              void* d_out, int out_size, void* d_ws, size_t ws_size,
                              hipStream_t stream) {
    const float* x = (const float*)d_in[0];
    const int* adj = (const int*)d_in[1];
    const float* W_att = (const float*)d_in[2];
    const float* a_att = (const float*)d_in[3];
    const float* W_out1 = (const float*)d_in[4];
    const float* a_out1 = (const float*)d_in[5];
    const float* W_out2 = (const float*)d_in[6];
    const float* a_out2 = (const float*)d_in[7];
    const float* W_down = (const float*)d_in[8];
    const float* b_down = (const float*)d_in[9];
    const float* w_deg = (const float*)d_in[10];
    const float* b_deg = (const float*)d_in[11];
    const float* W_deg3 = (const float*)d_in[12];
    const float* b_deg3 = (const float*)d_in[13];
    float* out = (float*)d_out;

    constexpr int N = 4096, NF = 512, NH = 64, NC = 16, H = 8, DM = 128;

    char* wp = (char*)d_ws;
    auto alloc = [&](size_t b) {
        char* p = wp;
        wp += (b + 255) & ~(size_t)255;
        return p;
    };
    unsigned long long* mask = (unsigned long long*)alloc((size_t)N * N / 8);
    unsigned short* xb = (unsigned short*)alloc((size_t)N * NF * 2);
    unsigned short* WT = (unsigned short*)alloc((size_t)656 * NF * 2);   // 10x64 + 16 rows
    unsigned short* Wd3T = (unsigned short*)alloc((size_t)DM * NH * 2);
    unsigned short* WhT = (unsigned short*)alloc((size_t)9 * NH * N * 2);  // 8 heads + origT
    float* f1h = (float*)alloc((size_t)H * N * 4);
    float* f2h = (float*)alloc((size_t)H * N * 4);
    uint2* pnh = (uint2*)alloc((size_t)H * 2048 * 8);
    float* M2 = (float*)alloc(256);
    float* parth = (float*)alloc((size_t)16 * N * NH * 4);
    float* Zh = (float*)alloc((size_t)16 * N * 4);
    unsigned short* hcb = (unsigned short*)alloc((size_t)N * NF * 2);
    unsigned short* Wh12T = (unsigned short*)alloc((size_t)80 * N * 2);
    float* f1o = (float*)alloc((size_t)2 * N * 4);
    float* f2o = (float*)alloc((size_t)2 * N * 4);
    uint2* pno = (uint2*)alloc((size_t)2 * 2048 * 8);
    float* part2 = (float*)alloc((size_t)8 * N * NH * 4);
    float* Z2 = (float*)alloc((size_t)8 * N * 4);
    float* part1 = (float*)alloc((size_t)8 * N * NC * 4);
    float* Z1 = (float*)alloc((size_t)8 * N * 4);
    float* zbuf = (float*)alloc((size_t)N * NH * 4);
    unsigned short* zb = (unsigned short*)alloc((size_t)N * NH * 2);

    const unsigned* mask32 = (const unsigned*)mask;

    // 1. prep: pack mask + x->bf16 + all weight transposes (one region dispatch)
    prep_k<<<66896, 256, 0, stream>>>(adj, mask, x, xb, W_att, W_down, W_out2, W_out1,
                                      W_deg3, WT, Wd3T);
    // 2. 9-slice batched GEMM: WhT[0..7] = (xb@W_att[h])^T fp16, WhT[8] = origT
    gemmb_k<64, 1><<<dim3(N / 128, 1, 9), 256, 0, stream>>>(
        (const __hip_bfloat16*)xb, (const __hip_bfloat16*)WT, nullptr, WhT, N, NH, NF);
    // 3. f1/f2 per head; max+pn tables
    fvh_k<<<dim3(16, H), 256, 0, stream>>>((const _Float16*)WhT, a_att, f1h, f2h);
    rmaxpn_k<<<H, 256, 0, stream>>>(f2h, M2, pnh);
    // 4. 8-head fp16 MFMA attention (2-way j-split, full occupancy) + combine
    attnh_k<<<dim3(N / 64, H, 2), 256, 0, stream>>>((const _Float16*)WhT, f1h, pnh, M2,
                                                    mask32, parth, Zh);
    combH_k<<<(size_t)N * 512 / 256, 256, 0, stream>>>(parth, Zh, hcb, N);
    // 5. fused out-projection GEMM (80 stacked cols) + f-vectors + max/pn
    gemmb_k<16, 1><<<dim3(N / 128, 5, 1), 256, 0, stream>>>(
        (const __hip_bfloat16*)hcb, (const __hip_bfloat16*)(WT + (size_t)9 * NH * NF),
        nullptr, Wh12T, N, 80, NF);
    fvo_k<<<dim3(16, 2), 256, 0, stream>>>((const _Float16*)Wh12T, a_out2, a_out1, f1o, f2o);
    rmaxpn_k<<<2, 256, 0, stream>>>(f2o, M2 + 8, pno);
    // 6. fused out2/out1 attention (8-way j-split)
    attno_k<<<dim3(N / 64, 2, 8), 256, 0, stream>>>((const _Float16*)Wh12T, f1o, pno, M2,
                                                    mask32, part2, Z2, part1, Z1);
    comb2_k<<<(size_t)N * 64 / 256, 256, 0, stream>>>(
        part2, Z2, (const _Float16*)(WhT + (size_t)8 * NH * N), b_down, zbuf, zb, N);
    // 7. outputs
    c1fin_k<<<N / 256, 256, 0, stream>>>(part1, Z1, zbuf, w_deg, b_deg, out, N);
    gemmb_k<64, 0><<<dim3(N / 128, DM / 64, 1), 256, 0, stream>>>(
        (const __hip_bfloat16*)zb, (const __hip_bfloat16*)Wd3T, b_deg3,
        out + (size_t)N * NC + N, N, DM, NH);
}